// Round 1
// baseline (927.719 us; speedup 1.0000x reference)
//
#include <hip/hip_runtime.h>
#include <cmath>

// Problem constants
#define TT 500
#define BB 8
#define CH 512
#define BC 4096            // B*C
#define NTOT 2048000       // T*B*C
#define HH 8
#define DD 64
#define WW 20

// ---------------------------------------------------------------------------
// GEMM: out[m,n] = sum_k A[m,k] * W[n,k], K=512, N covered by up to 3 weight
// tensors of 512 columns each. BM=BN=128, BK=16, 256 threads, 8x8 microtile.
// ---------------------------------------------------------------------------
__global__ __launch_bounds__(256) void gemm_k(
    const float* __restrict__ A,
    const float* __restrict__ W0, const float* __restrict__ W1, const float* __restrict__ W2,
    float* __restrict__ out, int M)
{
    __shared__ float As[16][132];
    __shared__ float Bs[16][132];
    int tid = threadIdx.x;
    int mBase = blockIdx.x * 128;
    int nBase = blockIdx.y * 128;
    int wsel = nBase >> 9;
    const float* Wp = (wsel == 0) ? W0 : ((wsel == 1) ? W1 : W2);
    int col0 = nBase & 511;
    int ty = tid >> 4, tx = tid & 15;
    int ldRow = tid >> 2;          // 0..63
    int ldK = (tid & 3) * 4;       // 0,4,8,12
    float acc[8][8] = {};

    for (int kt = 0; kt < 512; kt += 16) {
#pragma unroll
        for (int l = 0; l < 2; ++l) {
            int row = ldRow + l * 64;
            int m = mBase + row;
            float4 a4 = make_float4(0.f, 0.f, 0.f, 0.f);
            if (m < M) a4 = *(const float4*)(A + (size_t)m * 512 + kt + ldK);
            As[ldK + 0][row] = a4.x; As[ldK + 1][row] = a4.y;
            As[ldK + 2][row] = a4.z; As[ldK + 3][row] = a4.w;
            int wn = col0 + row;
            float4 b4 = *(const float4*)(Wp + (size_t)wn * 512 + kt + ldK);
            Bs[ldK + 0][row] = b4.x; Bs[ldK + 1][row] = b4.y;
            Bs[ldK + 2][row] = b4.z; Bs[ldK + 3][row] = b4.w;
        }
        __syncthreads();
#pragma unroll
        for (int kk = 0; kk < 16; ++kk) {
            float4 a0 = *(const float4*)&As[kk][ty * 8];
            float4 a1 = *(const float4*)&As[kk][ty * 8 + 4];
            float4 b0 = *(const float4*)&Bs[kk][tx * 8];
            float4 b1 = *(const float4*)&Bs[kk][tx * 8 + 4];
            float av[8] = {a0.x, a0.y, a0.z, a0.w, a1.x, a1.y, a1.z, a1.w};
            float bv[8] = {b0.x, b0.y, b0.z, b0.w, b1.x, b1.y, b1.z, b1.w};
#pragma unroll
            for (int i = 0; i < 8; ++i)
#pragma unroll
                for (int j = 0; j < 8; ++j)
                    acc[i][j] = fmaf(av[i], bv[j], acc[i][j]);
        }
        __syncthreads();
    }
    size_t tbase = (size_t)wsel * ((size_t)M * 512);
#pragma unroll
    for (int i = 0; i < 8; ++i) {
        int m = mBase + ty * 8 + i;
        if (m < M) {
            float4 o0 = make_float4(acc[i][0], acc[i][1], acc[i][2], acc[i][3]);
            float4 o1 = make_float4(acc[i][4], acc[i][5], acc[i][6], acc[i][7]);
            *(float4*)(out + tbase + (size_t)m * 512 + col0 + tx * 8) = o0;
            *(float4*)(out + tbase + (size_t)m * 512 + col0 + tx * 8 + 4) = o1;
        }
    }
}

// ---------------------------------------------------------------------------
// BN stats: partial sums per channel over row chunks, then finalize in f64.
// Channels may span multiple tensors of 512 (tensor stride NTOT).
// ---------------------------------------------------------------------------
__global__ __launch_bounds__(256) void bnstats_partial_k(
    const float* __restrict__ base, int rowsPerChunk, float* __restrict__ partial, int CT)
{
    int ch = blockIdx.x * 256 + threadIdx.x;
    int tensor = ch >> 9;
    int c = ch & 511;
    const float* p = base + (size_t)tensor * NTOT + c;
    int r0 = blockIdx.y * rowsPerChunk;
    float s = 0.f, s2 = 0.f;
    for (int r = 0; r < rowsPerChunk; ++r) {
        float v = p[(size_t)(r0 + r) * 512];
        s += v;
        s2 = fmaf(v, v, s2);
    }
    partial[((size_t)blockIdx.y * CT + ch) * 2 + 0] = s;
    partial[((size_t)blockIdx.y * CT + ch) * 2 + 1] = s2;
}

__global__ __launch_bounds__(256) void bnstats_final_k(
    const float* __restrict__ partial, int CT, int chunks,
    const float* __restrict__ gamma, const float* __restrict__ beta,
    float* __restrict__ scale, float* __restrict__ shift)
{
    int ch = blockIdx.x * 256 + threadIdx.x;
    if (ch >= CT) return;
    double s = 0.0, s2 = 0.0;
    for (int k = 0; k < chunks; ++k) {
        s  += (double)partial[((size_t)k * CT + ch) * 2 + 0];
        s2 += (double)partial[((size_t)k * CT + ch) * 2 + 1];
    }
    double mean = s / 4000.0;
    double var = s2 / 4000.0 - mean * mean;
    double sc = (double)gamma[ch] / sqrt(var + 1e-5);
    scale[ch] = (float)sc;
    shift[ch] = (float)((double)beta[ch] - mean * sc);
}

// ---------------------------------------------------------------------------
// Fused BN-apply + LIF scan.  One thread per (tensor, b, c) chain.
// useBN==0 -> identity (plain LIF).  out gets spikes {0,1}.
// ---------------------------------------------------------------------------
__global__ __launch_bounds__(256) void bn_lif_k(
    const float* __restrict__ pre, const float* __restrict__ scale,
    const float* __restrict__ shift, float* __restrict__ out, int useBN)
{
    int gid = blockIdx.x * 256 + threadIdx.x;
    int tensor = gid >> 12;
    int bc = gid & 4095;
    int ch = (tensor << 9) | (bc & 511);
    float sc = useBN ? scale[ch] : 1.f;
    float sh = useBN ? shift[ch] : 0.f;
    const float* p = pre + (size_t)tensor * NTOT + bc;
    float* o = out + (size_t)tensor * NTOT + bc;
    float v = 0.f;
    float xn = p[0];
    for (int t = 0; t < TT; ++t) {
        float x = xn;
        if (t + 1 < TT) xn = p[(size_t)(t + 1) * 4096];   // prefetch next step
        float bnx = fmaf(x, sc, sh);
        float h = fmaf(0.5f, v, bnx);                      // v - v/2 + x  (TAU=2)
        float spk = (h >= 1.f) ? 1.f : 0.f;
        v = (h >= 1.f) ? 0.f : h;
        o[(size_t)t * 4096] = spk;
    }
}

// ---------------------------------------------------------------------------
// KtV: ktv[b,h,d1,d2] = sum_t k[b,h,t,d1]*v[b,h,t,d2]  (exact integers)
// ---------------------------------------------------------------------------
__global__ __launch_bounds__(256) void ktv_k(
    const float* __restrict__ kspk, const float* __restrict__ vspk, float* __restrict__ ktv)
{
    __shared__ float kb[8][64], vb[8][64];
    int bh = blockIdx.x;
    int b = bh >> 3, h = bh & 7;
    int tid = threadIdx.x;
    int d1b = (tid >> 4) * 4, d2b = (tid & 15) * 4;
    float acc[4][4] = {};
    size_t cb = (size_t)b * 512 + h * 64;
    for (int tt = 0; tt < TT; tt += 8) {
#pragma unroll
        for (int l = 0; l < 2; ++l) {
            int idx = tid + l * 256;
            int tl = idx >> 6, d = idx & 63;
            int t = tt + tl;
            float kv = 0.f, vv = 0.f;
            if (t < TT) {
                kv = kspk[(size_t)t * 4096 + cb + d];
                vv = vspk[(size_t)t * 4096 + cb + d];
            }
            kb[tl][d] = kv;
            vb[tl][d] = vv;
        }
        __syncthreads();
#pragma unroll
        for (int tl = 0; tl < 8; ++tl) {
            float4 k4 = *(const float4*)&kb[tl][d1b];
            float4 v4 = *(const float4*)&vb[tl][d2b];
            float ka[4] = {k4.x, k4.y, k4.z, k4.w};
            float va[4] = {v4.x, v4.y, v4.z, v4.w};
#pragma unroll
            for (int i = 0; i < 4; ++i)
#pragma unroll
                for (int j = 0; j < 4; ++j)
                    acc[i][j] = fmaf(ka[i], va[j], acc[i][j]);
        }
        __syncthreads();
    }
    size_t ob = (size_t)bh * 64 * 64;
#pragma unroll
    for (int i = 0; i < 4; ++i)
        *(float4*)(ktv + ob + (size_t)(d1b + i) * 64 + d2b) =
            make_float4(acc[i][0], acc[i][1], acc[i][2], acc[i][3]);
}

// ---------------------------------------------------------------------------
// Global attention apply: g_pre[t,b,c] = gscale * sum_d1 q[t,b,h*64+d1]*ktv[b,h,d1,d2]
// ---------------------------------------------------------------------------
__global__ __launch_bounds__(256) void gapply_k(
    const float* __restrict__ qspk, const float* __restrict__ ktv,
    float* __restrict__ gpre, float gscale)
{
    __shared__ float qrow[512];
    int t = blockIdx.x, b = blockIdx.y;
    int tid = threadIdx.x;
    size_t rbase = (size_t)t * 4096 + (size_t)b * 512;
    qrow[tid] = qspk[rbase + tid];
    qrow[tid + 256] = qspk[rbase + tid + 256];
    __syncthreads();
#pragma unroll
    for (int oi = 0; oi < 2; ++oi) {
        int c = tid + oi * 256;
        int h = c >> 6, d2 = c & 63;
        const float* kt = ktv + ((size_t)(b * 8 + h) * 64) * 64 + d2;
        const float* qr = qrow + h * 64;
        float acc = 0.f;
#pragma unroll
        for (int d1 = 0; d1 < 64; ++d1)
            acc = fmaf(qr[d1], kt[(size_t)d1 * 64], acc);
        gpre[rbase + c] = acc * gscale;
    }
}

// ---------------------------------------------------------------------------
// Local banded attention: out[t] = lscale * sum_{o=-20..20} dot(q[t],k[t+o]) v[t+o]
// Block = (b,h, 32-t tile). LDS tiles for q(32), k/v(72 rows), scores (32x72).
// ---------------------------------------------------------------------------
__global__ __launch_bounds__(256) void local_k(
    const float* __restrict__ qspk, const float* __restrict__ kspk,
    const float* __restrict__ vspk, float* __restrict__ lpre, float lscale)
{
    __shared__ float qs[32][64];
    __shared__ float ks[72][64];
    __shared__ float vs[72][64];
    __shared__ float sm[32][72];
    int t0 = blockIdx.x * 32;
    int bh = blockIdx.y;
    int b = bh >> 3, h = bh & 7;
    int tid = threadIdx.x;
    size_t cb = (size_t)b * 512 + h * 64;

    for (int idx = tid; idx < 2048; idx += 256) {
        int tl = idx >> 6, d = idx & 63;
        int t = t0 + tl;
        qs[tl][d] = (t < TT) ? qspk[(size_t)t * 4096 + cb + d] : 0.f;
    }
    for (int idx = tid; idx < 4608; idx += 256) {
        int ul = idx >> 6, d = idx & 63;
        int u = t0 - WW + ul;
        bool in = (u >= 0 && u < TT);
        ks[ul][d] = in ? kspk[(size_t)u * 4096 + cb + d] : 0.f;
        vs[ul][d] = in ? vspk[(size_t)u * 4096 + cb + d] : 0.f;
    }
    __syncthreads();

    // Phase A: scores. thread -> t=tid/8, covers 9 u values (stride 8).
    int tA = tid >> 3;
    int ug = tid & 7;
    float4 qreg[16];
#pragma unroll
    for (int i = 0; i < 16; ++i) qreg[i] = *(const float4*)&qs[tA][i * 4];
#pragma unroll
    for (int ui = 0; ui < 9; ++ui) {
        int u = ug + ui * 8;
        float acc = 0.f;
#pragma unroll
        for (int i = 0; i < 16; ++i) {
            float4 k4 = *(const float4*)&ks[u][i * 4];
            acc = fmaf(qreg[i].x, k4.x, acc);
            acc = fmaf(qreg[i].y, k4.y, acc);
            acc = fmaf(qreg[i].z, k4.z, acc);
            acc = fmaf(qreg[i].w, k4.w, acc);
        }
        sm[tA][u] = acc;
    }
    __syncthreads();

    // Phase B: out[t][d] = sum_{o=0..40} s[t][t+o] * v[t+o][d]
#pragma unroll
    for (int oi = 0; oi < 2; ++oi) {
        int idx = tid + oi * 256;
        int t = idx >> 4;
        int dg = (idx & 15) * 4;
        float4 acc = make_float4(0.f, 0.f, 0.f, 0.f);
        for (int o = 0; o < 41; ++o) {
            int u = t + o;
            float s = sm[t][u];
            float4 v4 = *(const float4*)&vs[u][dg];
            acc.x = fmaf(s, v4.x, acc.x);
            acc.y = fmaf(s, v4.y, acc.y);
            acc.z = fmaf(s, v4.z, acc.z);
            acc.w = fmaf(s, v4.w, acc.w);
        }
        int tg = t0 + t;
        if (tg < TT) {
            acc.x *= lscale; acc.y *= lscale; acc.z *= lscale; acc.w *= lscale;
            *(float4*)(lpre + (size_t)tg * 4096 + cb + dg) = acc;
        }
    }
}

// ---------------------------------------------------------------------------
// Depthwise temporal conv (kernel 9, pad 4) on v spikes.
// ---------------------------------------------------------------------------
__global__ __launch_bounds__(256) void dwconv_k(
    const float* __restrict__ vspk, const float* __restrict__ wdw, float* __restrict__ dwpre)
{
    size_t e = (size_t)blockIdx.x * 256 + threadIdx.x;
    if (e >= (size_t)NTOT) return;
    int t = (int)(e >> 12);
    int bc = (int)(e & 4095);
    int h = (bc >> 6) & 7;
    float acc = 0.f;
#pragma unroll
    for (int j = 0; j < 9; ++j) {
        int ts = t + j - 4;
        if (ts >= 0 && ts < TT)
            acc = fmaf(wdw[h * 9 + j], vspk[(size_t)ts * 4096 + bc], acc);
    }
    dwpre[e] = acc;
}

// ---------------------------------------------------------------------------
// y0 = LIF( g_spk + l_spk + pw-mix(dw_spk) ), one thread per (b,c) chain.
// ---------------------------------------------------------------------------
__global__ __launch_bounds__(256) void y0_k(
    const float* __restrict__ gspk, const float* __restrict__ lspk,
    const float* __restrict__ dwspk, const float* __restrict__ wpw, float* __restrict__ y0)
{
    int bc = blockIdx.x * 256 + threadIdx.x;   // 0..4095
    int g = (bc >> 6) & 7;
    int d = bc & 63;
    int b512 = bc & ~511;
    float w[8];
#pragma unroll
    for (int hh = 0; hh < 8; ++hh) w[hh] = wpw[g * 8 + hh];
    float v = 0.f;
    for (int t = 0; t < TT; ++t) {
        size_t tb = (size_t)t * 4096;
        float x = gspk[tb + bc] + lspk[tb + bc];
#pragma unroll
        for (int hh = 0; hh < 8; ++hh)
            x = fmaf(w[hh], dwspk[tb + b512 + hh * 64 + d], x);
        float h = fmaf(0.5f, v, x);
        float s = (h >= 1.f) ? 1.f : 0.f;
        v = (h >= 1.f) ? 0.f : h;
        y0[tb + bc] = s;
    }
}

// ---------------------------------------------------------------------------
extern "C" void kernel_launch(void* const* d_in, const int* in_sizes, int n_in,
                              void* d_out, int out_size, void* d_ws, size_t ws_size,
                              hipStream_t stream)
{
    const float* x       = (const float*)d_in[0];
    const float* wq      = (const float*)d_in[1];
    const float* wk      = (const float*)d_in[2];
    const float* wv      = (const float*)d_in[3];
    const float* w_mattn = (const float*)d_in[4];
    const float* w_proj  = (const float*)d_in[5];
    const float* w_dw    = (const float*)d_in[6];
    const float* w_pw    = (const float*)d_in[7];
    const float* bn_g    = (const float*)d_in[8];
    const float* bn_b    = (const float*)d_in[9];
    float* out = (float*)d_out;

    float* ws = (float*)d_ws;
    float* slot0 = ws + 0 * (size_t)NTOT;
    float* slot1 = ws + 1 * (size_t)NTOT;
    float* slot2 = ws + 2 * (size_t)NTOT;
    float* slot3 = ws + 3 * (size_t)NTOT;
    float* slot4 = ws + 4 * (size_t)NTOT;
    float* slot5 = ws + 5 * (size_t)NTOT;
    float* ktv     = ws + 6 * (size_t)NTOT;           // 262144
    float* partial = ktv + 262144;                    // 20*1536*2 = 61440
    float* sc_qkv  = partial + 61440;                 // 1536
    float* sh_qkv  = sc_qkv + 1536;                   // 1536
    float* sc_m    = sh_qkv + 1536;                   // 512
    float* sh_m    = sc_m + 512;
    float* sc_p    = sh_m + 512;
    float* sh_p    = sc_p + 512;

    // scales exactly as reference computes them (sqrt in f64, cast f32, 1/x in f64)
    float gs32 = (float)std::sqrt((double)(DD * (1000 / 2)));   // sqrt(32000) -> f32
    float gscale = (float)(1.0 / (double)gs32);
    float ls32 = (float)std::sqrt((double)(DD * (2 * WW + 1))); // sqrt(2624) -> f32
    float lscale = (float)(1.0 / (double)ls32);

    const int M = TT * BB;   // 4000

    // 1) fused QKV GEMM -> slot0/1/2
    gemm_k<<<dim3(32, 12), 256, 0, stream>>>(x, wq, wk, wv, slot0, M);
    // 2) BN stats (3 tensors, 1536 channels)
    bnstats_partial_k<<<dim3(6, 20), 256, 0, stream>>>(slot0, 200, partial, 1536);
    bnstats_final_k<<<6, 256, 0, stream>>>(partial, 1536, 20, bn_g, bn_b, sc_qkv, sh_qkv);
    // 3) BN+LIF -> q/k/v spikes in slot3/4/5
    bn_lif_k<<<48, 256, 0, stream>>>(slot0, sc_qkv, sh_qkv, slot3, 1);
    // 4) global branch: KtV then Q(KtV)
    ktv_k<<<64, 256, 0, stream>>>(slot4, slot5, ktv);
    gapply_k<<<dim3(500, 8), 256, 0, stream>>>(slot3, ktv, slot0, gscale);   // g_pre -> slot0
    // 5) local banded attention -> slot1
    local_k<<<dim3(16, 64), 256, 0, stream>>>(slot3, slot4, slot5, slot1, lscale);
    // 6) depthwise conv on v -> slot2
    dwconv_k<<<8000, 256, 0, stream>>>(slot5, w_dw, slot2);
    // 7) LIF on g/l/dw (no BN) -> spikes slot3/4/5
    bn_lif_k<<<48, 256, 0, stream>>>(slot0, nullptr, nullptr, slot3, 0);
    // 8) y0 = LIF(g + l + pw-mix(dw)) -> slot0
    y0_k<<<16, 256, 0, stream>>>(slot3, slot4, slot5, w_pw, slot0);
    // 9) mattn GEMM + BN + LIF -> y1 spikes slot2
    gemm_k<<<dim3(32, 4), 256, 0, stream>>>(slot0, w_mattn, w_mattn, w_mattn, slot1, M);
    bnstats_partial_k<<<dim3(2, 20), 256, 0, stream>>>(slot1, 200, partial, 512);
    bnstats_final_k<<<2, 256, 0, stream>>>(partial, 512, 20, bn_g + 3 * 512, bn_b + 3 * 512, sc_m, sh_m);
    bn_lif_k<<<16, 256, 0, stream>>>(slot1, sc_m, sh_m, slot2, 1);
    // 10) proj GEMM + BN + LIF -> final output
    gemm_k<<<dim3(32, 4), 256, 0, stream>>>(slot2, w_proj, w_proj, w_proj, slot3, M);
    bnstats_partial_k<<<dim3(2, 20), 256, 0, stream>>>(slot3, 200, partial, 512);
    bnstats_final_k<<<2, 256, 0, stream>>>(partial, 512, 20, bn_g + 4 * 512, bn_b + 4 * 512, sc_p, sh_p);
    bn_lif_k<<<16, 256, 0, stream>>>(slot3, sc_p, sh_p, out, 1);

    (void)in_sizes; (void)n_in; (void)out_size; (void)ws_size;
}

// Round 2
// 693.155 us; speedup vs baseline: 1.3384x; 1.3384x over previous
//
#include <hip/hip_runtime.h>
#include <cmath>

// Problem constants
#define TT 500
#define BB 8
#define CH 512
#define NTOT 2048000       // T*B*C
#define HH 8
#define DD 64
#define WW 20

// ---------------------------------------------------------------------------
// GEMM: out[m,n] = sum_{k in [kBase,kBase+kLen)} A[m,k] * W[n,k].
// BM=BN=128, BK=16, 256 threads, 8x8 microtile with split columns/rows
// (ty*4 / 64+ty*4, tx*4 / 64+tx*4) for conflict-free LDS reads.
// blockIdx.z selects the K-half; output half z goes to out + z*halfStride.
// ---------------------------------------------------------------------------
__global__ __launch_bounds__(256) void gemm_k(
    const float* __restrict__ A,
    const float* __restrict__ W0, const float* __restrict__ W1, const float* __restrict__ W2,
    float* __restrict__ out, int M, int kLen, long long halfStride)
{
    __shared__ __align__(16) float As[16][132];
    __shared__ __align__(16) float Bs[16][132];
    int tid = threadIdx.x;
    int mBase = blockIdx.x * 128;
    int nBase = blockIdx.y * 128;
    int kBase = blockIdx.z * kLen;
    int wsel = nBase >> 9;
    const float* Wp = (wsel == 0) ? W0 : ((wsel == 1) ? W1 : W2);
    int col0 = nBase & 511;
    int ty = tid >> 4, tx = tid & 15;
    int ldRow = tid >> 2;          // 0..63
    int ldK = (tid & 3) * 4;       // 0,4,8,12
    float acc[8][8] = {};

    for (int kt = kBase; kt < kBase + kLen; kt += 16) {
#pragma unroll
        for (int l = 0; l < 2; ++l) {
            int row = ldRow + l * 64;
            int m = mBase + row;
            float4 a4 = make_float4(0.f, 0.f, 0.f, 0.f);
            if (m < M) a4 = *(const float4*)(A + (size_t)m * 512 + kt + ldK);
            As[ldK + 0][row] = a4.x; As[ldK + 1][row] = a4.y;
            As[ldK + 2][row] = a4.z; As[ldK + 3][row] = a4.w;
            int wn = col0 + row;
            float4 b4 = *(const float4*)(Wp + (size_t)wn * 512 + kt + ldK);
            Bs[ldK + 0][row] = b4.x; Bs[ldK + 1][row] = b4.y;
            Bs[ldK + 2][row] = b4.z; Bs[ldK + 3][row] = b4.w;
        }
        __syncthreads();
#pragma unroll
        for (int kk = 0; kk < 16; ++kk) {
            float4 a0 = *(const float4*)&As[kk][ty * 4];
            float4 a1 = *(const float4*)&As[kk][64 + ty * 4];
            float4 b0 = *(const float4*)&Bs[kk][tx * 4];
            float4 b1 = *(const float4*)&Bs[kk][64 + tx * 4];
            float av[8] = {a0.x, a0.y, a0.z, a0.w, a1.x, a1.y, a1.z, a1.w};
            float bv[8] = {b0.x, b0.y, b0.z, b0.w, b1.x, b1.y, b1.z, b1.w};
#pragma unroll
            for (int i = 0; i < 8; ++i)
#pragma unroll
                for (int j = 0; j < 8; ++j)
                    acc[i][j] = fmaf(av[i], bv[j], acc[i][j]);
        }
        __syncthreads();
    }
    float* outp = out + (long long)blockIdx.z * halfStride + (size_t)wsel * NTOT;
#pragma unroll
    for (int ih = 0; ih < 2; ++ih)
#pragma unroll
        for (int i = 0; i < 4; ++i) {
            int m = mBase + ih * 64 + ty * 4 + i;
            if (m < M) {
                float* r = outp + (size_t)m * 512 + col0;
                int ai = ih * 4 + i;
                *(float4*)(r + tx * 4) =
                    make_float4(acc[ai][0], acc[ai][1], acc[ai][2], acc[ai][3]);
                *(float4*)(r + 64 + tx * 4) =
                    make_float4(acc[ai][4], acc[ai][5], acc[ai][6], acc[ai][7]);
            }
        }
}

// ---------------------------------------------------------------------------
// BN stats over (optionally) two K-halves summed elementwise.
// ---------------------------------------------------------------------------
__global__ __launch_bounds__(256) void bnstats_partial_k(
    const float* __restrict__ base0, const float* __restrict__ base1,
    int rowsPerChunk, float* __restrict__ partial, int CT)
{
    int ch = blockIdx.x * 256 + threadIdx.x;
    int tensor = ch >> 9;
    int c = ch & 511;
    const float* p = base0 + (size_t)tensor * NTOT + c;
    const float* q = base1 ? (base1 + (size_t)tensor * NTOT + c) : p;
    float addf = base1 ? 1.f : 0.f;
    int r0 = blockIdx.y * rowsPerChunk;
    float s = 0.f, s2 = 0.f;
    for (int r = 0; r < rowsPerChunk; ++r) {
        size_t off = (size_t)(r0 + r) * 512;
        float v = fmaf(addf, q[off], p[off]);
        s += v;
        s2 = fmaf(v, v, s2);
    }
    partial[((size_t)blockIdx.y * CT + ch) * 2 + 0] = s;
    partial[((size_t)blockIdx.y * CT + ch) * 2 + 1] = s2;
}

__global__ __launch_bounds__(256) void bnstats_final_k(
    const float* __restrict__ partial, int CT, int chunks,
    const float* __restrict__ gamma, const float* __restrict__ beta,
    float* __restrict__ scale, float* __restrict__ shift)
{
    int ch = blockIdx.x * 256 + threadIdx.x;
    if (ch >= CT) return;
    double s = 0.0, s2 = 0.0;
    for (int k = 0; k < chunks; ++k) {
        s  += (double)partial[((size_t)k * CT + ch) * 2 + 0];
        s2 += (double)partial[((size_t)k * CT + ch) * 2 + 1];
    }
    double mean = s / 4000.0;
    double var = s2 / 4000.0 - mean * mean;
    double sc = (double)gamma[ch] / sqrt(var + 1e-5);
    scale[ch] = (float)sc;
    shift[ch] = (float)((double)beta[ch] - mean * sc);
}

// ---------------------------------------------------------------------------
// Fused (optional half-sum) + BN-apply + LIF scan, software-pipelined x10.
// One thread per (tensor, b, c) chain; 500 = 50 groups of 10.
// ---------------------------------------------------------------------------
__global__ __launch_bounds__(256) void bn_lif_k(
    const float* __restrict__ p0, const float* __restrict__ p1,
    const float* __restrict__ scale, const float* __restrict__ shift,
    float* __restrict__ out, int useBN)
{
    int gid = blockIdx.x * 256 + threadIdx.x;
    int tensor = gid >> 12;
    int bc = gid & 4095;
    int ch = (tensor << 9) | (bc & 511);
    float sc = useBN ? scale[ch] : 1.f;
    float sh = useBN ? shift[ch] : 0.f;
    const float* q0 = p0 + (size_t)tensor * NTOT + bc;
    const float* q1 = p1 ? (p1 + (size_t)tensor * NTOT + bc) : q0;
    float addf = p1 ? 1.f : 0.f;
    float* o = out + (size_t)tensor * NTOT + bc;
    float v = 0.f;
    float b0[10], b1[10];
#pragma unroll
    for (int j = 0; j < 10; ++j) {
        b0[j] = q0[(size_t)j * 4096];
        b1[j] = q1[(size_t)j * 4096];
    }
    for (int g = 0; g < 50; ++g) {
        float n0[10], n1[10];
        if (g < 49) {
#pragma unroll
            for (int j = 0; j < 10; ++j) {
                n0[j] = q0[(size_t)((g + 1) * 10 + j) * 4096];
                n1[j] = q1[(size_t)((g + 1) * 10 + j) * 4096];
            }
        } else {
#pragma unroll
            for (int j = 0; j < 10; ++j) { n0[j] = 0.f; n1[j] = 0.f; }
        }
#pragma unroll
        for (int j = 0; j < 10; ++j) {
            float x = fmaf(addf, b1[j], b0[j]);
            float bnx = fmaf(x, sc, sh);
            float h = fmaf(0.5f, v, bnx);
            float s = (h >= 1.f) ? 1.f : 0.f;
            v = (h >= 1.f) ? 0.f : h;
            o[(size_t)(g * 10 + j) * 4096] = s;
        }
#pragma unroll
        for (int j = 0; j < 10; ++j) { b0[j] = n0[j]; b1[j] = n1[j]; }
    }
}

// ---------------------------------------------------------------------------
// KtV: ktv[b,h,d1,d2] = sum_t k[b,h,t,d1]*v[b,h,t,d2]  (exact integers)
// TTILE=16 with register prefetch of the next tile.
// ---------------------------------------------------------------------------
__global__ __launch_bounds__(256) void ktv_k(
    const float* __restrict__ kspk, const float* __restrict__ vspk, float* __restrict__ ktv)
{
    __shared__ __align__(16) float kb[16][64], vb[16][64];
    int bh = blockIdx.x;
    int b = bh >> 3, h = bh & 7;
    int tid = threadIdx.x;
    int d1b = (tid >> 4) * 4, d2b = (tid & 15) * 4;
    size_t cb = (size_t)b * 512 + h * 64;
    float acc[4][4] = {};
    float pk[4], pv[4];
#pragma unroll
    for (int l = 0; l < 4; ++l) {
        int idx = tid + l * 256;
        int tl = idx >> 6, d = idx & 63;
        bool in = tl < TT;
        pk[l] = in ? kspk[(size_t)tl * 4096 + cb + d] : 0.f;
        pv[l] = in ? vspk[(size_t)tl * 4096 + cb + d] : 0.f;
    }
    for (int tt = 0; tt < TT; tt += 16) {
        __syncthreads();
#pragma unroll
        for (int l = 0; l < 4; ++l) {
            int idx = tid + l * 256;
            int tl = idx >> 6, d = idx & 63;
            kb[tl][d] = pk[l];
            vb[tl][d] = pv[l];
        }
        __syncthreads();
        if (tt + 16 < TT + 16) {  // prefetch next tile (guarded loads)
#pragma unroll
            for (int l = 0; l < 4; ++l) {
                int idx = tid + l * 256;
                int tl = idx >> 6, d = idx & 63;
                int t = tt + 16 + tl;
                bool in = t < TT;
                pk[l] = in ? kspk[(size_t)t * 4096 + cb + d] : 0.f;
                pv[l] = in ? vspk[(size_t)t * 4096 + cb + d] : 0.f;
            }
        }
#pragma unroll
        for (int tl = 0; tl < 16; ++tl) {
            float4 k4 = *(const float4*)&kb[tl][d1b];
            float4 v4 = *(const float4*)&vb[tl][d2b];
            float ka[4] = {k4.x, k4.y, k4.z, k4.w};
            float va[4] = {v4.x, v4.y, v4.z, v4.w};
#pragma unroll
            for (int i = 0; i < 4; ++i)
#pragma unroll
                for (int j = 0; j < 4; ++j)
                    acc[i][j] = fmaf(ka[i], va[j], acc[i][j]);
        }
    }
    size_t ob = (size_t)bh * 64 * 64;
#pragma unroll
    for (int i = 0; i < 4; ++i)
        *(float4*)(ktv + ob + (size_t)(d1b + i) * 64 + d2b) =
            make_float4(acc[i][0], acc[i][1], acc[i][2], acc[i][3]);
}

// ---------------------------------------------------------------------------
// Global attention apply: g_pre[t,b,c] = gscale * sum_d1 q[t,b,h*64+d1]*ktv[b,h,d1,d2]
// ---------------------------------------------------------------------------
__global__ __launch_bounds__(256) void gapply_k(
    const float* __restrict__ qspk, const float* __restrict__ ktv,
    float* __restrict__ gpre, float gscale)
{
    __shared__ float qrow[512];
    int t = blockIdx.x, b = blockIdx.y;
    int tid = threadIdx.x;
    size_t rbase = (size_t)t * 4096 + (size_t)b * 512;
    qrow[tid] = qspk[rbase + tid];
    qrow[tid + 256] = qspk[rbase + tid + 256];
    __syncthreads();
#pragma unroll
    for (int oi = 0; oi < 2; ++oi) {
        int c = tid + oi * 256;
        int h = c >> 6, d2 = c & 63;
        const float* kt = ktv + ((size_t)(b * 8 + h) * 64) * 64 + d2;
        const float* qr = qrow + h * 64;
        float acc = 0.f;
#pragma unroll
        for (int d1 = 0; d1 < 64; ++d1)
            acc = fmaf(qr[d1], kt[(size_t)d1 * 64], acc);
        gpre[rbase + c] = acc * gscale;
    }
}

// ---------------------------------------------------------------------------
// Local banded attention (unchanged from round 0).
// ---------------------------------------------------------------------------
__global__ __launch_bounds__(256) void local_k(
    const float* __restrict__ qspk, const float* __restrict__ kspk,
    const float* __restrict__ vspk, float* __restrict__ lpre, float lscale)
{
    __shared__ __align__(16) float qs[32][64];
    __shared__ __align__(16) float ks[72][64];
    __shared__ __align__(16) float vs[72][64];
    __shared__ float sm[32][72];
    int t0 = blockIdx.x * 32;
    int bh = blockIdx.y;
    int b = bh >> 3, h = bh & 7;
    int tid = threadIdx.x;
    size_t cb = (size_t)b * 512 + h * 64;

    for (int idx = tid; idx < 2048; idx += 256) {
        int tl = idx >> 6, d = idx & 63;
        int t = t0 + tl;
        qs[tl][d] = (t < TT) ? qspk[(size_t)t * 4096 + cb + d] : 0.f;
    }
    for (int idx = tid; idx < 4608; idx += 256) {
        int ul = idx >> 6, d = idx & 63;
        int u = t0 - WW + ul;
        bool in = (u >= 0 && u < TT);
        ks[ul][d] = in ? kspk[(size_t)u * 4096 + cb + d] : 0.f;
        vs[ul][d] = in ? vspk[(size_t)u * 4096 + cb + d] : 0.f;
    }
    __syncthreads();

    int tA = tid >> 3;
    int ug = tid & 7;
    float4 qreg[16];
#pragma unroll
    for (int i = 0; i < 16; ++i) qreg[i] = *(const float4*)&qs[tA][i * 4];
#pragma unroll
    for (int ui = 0; ui < 9; ++ui) {
        int u = ug + ui * 8;
        float acc = 0.f;
#pragma unroll
        for (int i = 0; i < 16; ++i) {
            float4 k4 = *(const float4*)&ks[u][i * 4];
            acc = fmaf(qreg[i].x, k4.x, acc);
            acc = fmaf(qreg[i].y, k4.y, acc);
            acc = fmaf(qreg[i].z, k4.z, acc);
            acc = fmaf(qreg[i].w, k4.w, acc);
        }
        sm[tA][u] = acc;
    }
    __syncthreads();

#pragma unroll
    for (int oi = 0; oi < 2; ++oi) {
        int idx = tid + oi * 256;
        int t = idx >> 4;
        int dg = (idx & 15) * 4;
        float4 acc = make_float4(0.f, 0.f, 0.f, 0.f);
        for (int o = 0; o < 41; ++o) {
            int u = t + o;
            float s = sm[t][u];
            float4 v4 = *(const float4*)&vs[u][dg];
            acc.x = fmaf(s, v4.x, acc.x);
            acc.y = fmaf(s, v4.y, acc.y);
            acc.z = fmaf(s, v4.z, acc.z);
            acc.w = fmaf(s, v4.w, acc.w);
        }
        int tg = t0 + t;
        if (tg < TT) {
            acc.x *= lscale; acc.y *= lscale; acc.z *= lscale; acc.w *= lscale;
            *(float4*)(lpre + (size_t)tg * 4096 + cb + dg) = acc;
        }
    }
}

// ---------------------------------------------------------------------------
// Depthwise temporal conv (kernel 9, pad 4), 4 consecutive t per thread.
// ---------------------------------------------------------------------------
__global__ __launch_bounds__(256) void dwconv_k(
    const float* __restrict__ vspk, const float* __restrict__ wdw, float* __restrict__ dwpre)
{
    int gid = blockIdx.x * 256 + threadIdx.x;   // 125 * 4096
    int tg = gid >> 12;
    int bc = gid & 4095;
    int t0 = tg * 4;
    int h = (bc >> 6) & 7;
    float w[9];
#pragma unroll
    for (int j = 0; j < 9; ++j) w[j] = wdw[h * 9 + j];
    float xv[12];
#pragma unroll
    for (int j = 0; j < 12; ++j) {
        int ts = t0 - 4 + j;
        xv[j] = (ts >= 0 && ts < TT) ? vspk[(size_t)ts * 4096 + bc] : 0.f;
    }
#pragma unroll
    for (int r = 0; r < 4; ++r) {
        float acc = 0.f;
#pragma unroll
        for (int j = 0; j < 9; ++j)
            acc = fmaf(w[j], xv[r + j], acc);
        dwpre[(size_t)(t0 + r) * 4096 + bc] = acc;
    }
}

// ---------------------------------------------------------------------------
// Pointwise head mix: out[t,b,g*64+d] = sum_h wpw[g,h] * dwspk[t,b,h*64+d]
// ---------------------------------------------------------------------------
__global__ __launch_bounds__(256) void mix_k(
    const float* __restrict__ dwspk, const float* __restrict__ wpw, float* __restrict__ out)
{
    size_t e = (size_t)blockIdx.x * 256 + threadIdx.x;
    int bc = (int)(e & 4095);
    int g = (bc >> 6) & 7;
    int d = bc & 63;
    int b512 = bc & ~511;
    size_t tb = e - bc;
    float acc = 0.f;
#pragma unroll
    for (int hh = 0; hh < 8; ++hh)
        acc = fmaf(wpw[g * 8 + hh], dwspk[tb + b512 + hh * 64 + d], acc);
    out[e] = acc;
}

// ---------------------------------------------------------------------------
// y0 = LIF(g_spk + l_spk + mix), pipelined x10.
// ---------------------------------------------------------------------------
__global__ __launch_bounds__(256) void y0_k(
    const float* __restrict__ a, const float* __restrict__ b,
    const float* __restrict__ c, float* __restrict__ out)
{
    int bc = blockIdx.x * 256 + threadIdx.x;   // 0..4095
    float v = 0.f;
    float ba[10], bb[10], bbc[10];
#pragma unroll
    for (int j = 0; j < 10; ++j) {
        size_t off = (size_t)j * 4096 + bc;
        ba[j] = a[off]; bb[j] = b[off]; bbc[j] = c[off];
    }
    for (int g = 0; g < 50; ++g) {
        float na[10], nb[10], nc[10];
        if (g < 49) {
#pragma unroll
            for (int j = 0; j < 10; ++j) {
                size_t off = (size_t)((g + 1) * 10 + j) * 4096 + bc;
                na[j] = a[off]; nb[j] = b[off]; nc[j] = c[off];
            }
        } else {
#pragma unroll
            for (int j = 0; j < 10; ++j) { na[j] = 0.f; nb[j] = 0.f; nc[j] = 0.f; }
        }
#pragma unroll
        for (int j = 0; j < 10; ++j) {
            float x = (ba[j] + bb[j]) + bbc[j];
            float h = fmaf(0.5f, v, x);
            float s = (h >= 1.f) ? 1.f : 0.f;
            v = (h >= 1.f) ? 0.f : h;
            out[(size_t)(g * 10 + j) * 4096 + bc] = s;
        }
#pragma unroll
        for (int j = 0; j < 10; ++j) { ba[j] = na[j]; bb[j] = nb[j]; bbc[j] = nc[j]; }
    }
}

// ---------------------------------------------------------------------------
extern "C" void kernel_launch(void* const* d_in, const int* in_sizes, int n_in,
                              void* d_out, int out_size, void* d_ws, size_t ws_size,
                              hipStream_t stream)
{
    const float* x       = (const float*)d_in[0];
    const float* wq      = (const float*)d_in[1];
    const float* wk      = (const float*)d_in[2];
    const float* wv      = (const float*)d_in[3];
    const float* w_mattn = (const float*)d_in[4];
    const float* w_proj  = (const float*)d_in[5];
    const float* w_dw    = (const float*)d_in[6];
    const float* w_pw    = (const float*)d_in[7];
    const float* bn_g    = (const float*)d_in[8];
    const float* bn_b    = (const float*)d_in[9];
    float* out = (float*)d_out;
    float* ws = (float*)d_ws;

    // scales exactly as reference computes them
    float gs32 = (float)std::sqrt((double)(DD * (1000 / 2)));
    float gscale = (float)(1.0 / (double)gs32);
    float ls32 = (float)std::sqrt((double)(DD * (2 * WW + 1)));
    float lscale = (float)(1.0 / (double)ls32);
    const int M = TT * BB;   // 4000

    size_t extras = 262144 + 61440 + 2 * 1536 + 4 * 512;
    size_t needSK = (9 * (size_t)NTOT + extras) * 4;
    bool sk = ws_size >= needSK;
    int nslots = sk ? 9 : 6;
    auto S = [&](int i) { return ws + (size_t)i * NTOT; };
    float* ktvBuf  = ws + (size_t)nslots * NTOT;
    float* partial = ktvBuf + 262144;
    float* sc_qkv  = partial + 61440;
    float* sh_qkv  = sc_qkv + 1536;
    float* sc_m    = sh_qkv + 1536;
    float* sh_m    = sc_m + 512;
    float* sc_p    = sh_m + 512;
    float* sh_p    = sc_p + 512;

    if (sk) {
        float* h0 = S(0);                 // QKV half0: tensors at +0,+NTOT,+2NTOT
        float* h1 = S(3);                 // QKV half1
        gemm_k<<<dim3(32, 12, 2), 256, 0, stream>>>(x, wq, wk, wv, h0, M, 256, (long long)3 * NTOT);
        bnstats_partial_k<<<dim3(6, 20), 256, 0, stream>>>(h0, h1, 200, partial, 1536);
        bnstats_final_k<<<6, 256, 0, stream>>>(partial, 1536, 20, bn_g, bn_b, sc_qkv, sh_qkv);
        bn_lif_k<<<48, 256, 0, stream>>>(h0, h1, sc_qkv, sh_qkv, S(6), 1);  // q,k,v -> S6,S7,S8
        ktv_k<<<64, 256, 0, stream>>>(S(7), S(8), ktvBuf);
        gapply_k<<<dim3(500, 8), 256, 0, stream>>>(S(6), ktvBuf, S(0), gscale);     // g_pre -> S0
        local_k<<<dim3(16, 64), 256, 0, stream>>>(S(6), S(7), S(8), S(1), lscale);  // l_pre -> S1
        dwconv_k<<<2000, 256, 0, stream>>>(S(8), w_dw, S(2));                       // dw_pre -> S2
        bn_lif_k<<<48, 256, 0, stream>>>(S(0), nullptr, nullptr, nullptr, S(3), 0); // spikes -> S3,S4,S5
        mix_k<<<8000, 256, 0, stream>>>(S(5), w_pw, S(2));                          // mix -> S2
        y0_k<<<16, 256, 0, stream>>>(S(3), S(4), S(2), S(6));                       // y0 -> S6
        gemm_k<<<dim3(32, 4, 2), 256, 0, stream>>>(S(6), w_mattn, w_mattn, w_mattn, S(7), M, 256, (long long)NTOT);
        bnstats_partial_k<<<dim3(2, 20), 256, 0, stream>>>(S(7), S(8), 200, partial, 512);
        bnstats_final_k<<<2, 256, 0, stream>>>(partial, 512, 20, bn_g + 1536, bn_b + 1536, sc_m, sh_m);
        bn_lif_k<<<16, 256, 0, stream>>>(S(7), S(8), sc_m, sh_m, S(0), 1);          // y1 -> S0
        gemm_k<<<dim3(32, 4, 2), 256, 0, stream>>>(S(0), w_proj, w_proj, w_proj, S(1), M, 256, (long long)NTOT);
        bnstats_partial_k<<<dim3(2, 20), 256, 0, stream>>>(S(1), S(2), 200, partial, 512);
        bnstats_final_k<<<2, 256, 0, stream>>>(partial, 512, 20, bn_g + 2048, bn_b + 2048, sc_p, sh_p);
        bn_lif_k<<<16, 256, 0, stream>>>(S(1), S(2), sc_p, sh_p, out, 1);
    } else {
        gemm_k<<<dim3(32, 12, 1), 256, 0, stream>>>(x, wq, wk, wv, S(0), M, 512, 0);
        bnstats_partial_k<<<dim3(6, 20), 256, 0, stream>>>(S(0), nullptr, 200, partial, 1536);
        bnstats_final_k<<<6, 256, 0, stream>>>(partial, 1536, 20, bn_g, bn_b, sc_qkv, sh_qkv);
        bn_lif_k<<<48, 256, 0, stream>>>(S(0), nullptr, sc_qkv, sh_qkv, S(3), 1);   // q,k,v -> S3,S4,S5
        ktv_k<<<64, 256, 0, stream>>>(S(4), S(5), ktvBuf);
        gapply_k<<<dim3(500, 8), 256, 0, stream>>>(S(3), ktvBuf, S(0), gscale);
        local_k<<<dim3(16, 64), 256, 0, stream>>>(S(3), S(4), S(5), S(1), lscale);
        dwconv_k<<<2000, 256, 0, stream>>>(S(5), w_dw, S(2));
        bn_lif_k<<<48, 256, 0, stream>>>(S(0), nullptr, nullptr, nullptr, S(3), 0); // -> S3,S4,S5
        mix_k<<<8000, 256, 0, stream>>>(S(5), w_pw, S(2));
        y0_k<<<16, 256, 0, stream>>>(S(3), S(4), S(2), S(0));                       // y0 -> S0
        gemm_k<<<dim3(32, 4, 1), 256, 0, stream>>>(S(0), w_mattn, w_mattn, w_mattn, S(1), M, 512, 0);
        bnstats_partial_k<<<dim3(2, 20), 256, 0, stream>>>(S(1), nullptr, 200, partial, 512);
        bnstats_final_k<<<2, 256, 0, stream>>>(partial, 512, 20, bn_g + 1536, bn_b + 1536, sc_m, sh_m);
        bn_lif_k<<<16, 256, 0, stream>>>(S(1), nullptr, sc_m, sh_m, S(2), 1);       // y1 -> S2
        gemm_k<<<dim3(32, 4, 1), 256, 0, stream>>>(S(2), w_proj, w_proj, w_proj, S(1), M, 512, 0);
        bnstats_partial_k<<<dim3(2, 20), 256, 0, stream>>>(S(1), nullptr, 200, partial, 512);
        bnstats_final_k<<<2, 256, 0, stream>>>(partial, 512, 20, bn_g + 2048, bn_b + 2048, sc_p, sh_p);
        bn_lif_k<<<16, 256, 0, stream>>>(S(1), nullptr, sc_p, sh_p, out, 1);
    }

    (void)in_sizes; (void)n_in; (void)out_size;
}

// Round 4
// 500.321 us; speedup vs baseline: 1.8542x; 1.3854x over previous
//
#include <hip/hip_runtime.h>
#include <cmath>

#define TT 500
#define NTOT 2048000       // T*B*C
#define WW 20

// ---------------------------------------------------------------------------
// GEMM: out[m,n] = sum_{k in [z*kLen,(z+1)*kLen)} A[m,k]*W[n,k].
// BM=128, BN=64, BK=16, 256 threads, 8x4 microtile, register prefetch.
// ---------------------------------------------------------------------------
__global__ __launch_bounds__(256) void gemm_k(
    const float* __restrict__ A,
    const float* __restrict__ W0, const float* __restrict__ W1, const float* __restrict__ W2,
    float* __restrict__ out, int M, int kLen, long long halfStride)
{
    __shared__ __align__(16) float As[16][132];
    __shared__ __align__(16) float Bs[16][68];
    int tid = threadIdx.x;
    int mBase = blockIdx.x * 128;
    int nBase = blockIdx.y * 64;
    int kBase = blockIdx.z * kLen;
    int kEnd = kBase + kLen;
    int wsel = nBase >> 9;
    const float* Wp = (wsel == 0) ? W0 : ((wsel == 1) ? W1 : W2);
    int col0 = nBase & 511;
    int ty = tid >> 4, tx = tid & 15;
    int ldRow = tid >> 2;          // 0..63
    int ldK = (tid & 3) * 4;       // 0,4,8,12
    float acc[8][4] = {};
    float4 pa[2], pb;

    auto loadT = [&](int kt) {
#pragma unroll
        for (int l = 0; l < 2; ++l) {
            int m = mBase + ldRow + l * 64;
            pa[l] = make_float4(0.f, 0.f, 0.f, 0.f);
            if (m < M) pa[l] = *(const float4*)(A + (size_t)m * 512 + kt + ldK);
        }
        pb = *(const float4*)(Wp + (size_t)(col0 + ldRow) * 512 + kt + ldK);
    };
    loadT(kBase);
    for (int kt = kBase; kt < kEnd; kt += 16) {
        __syncthreads();
#pragma unroll
        for (int l = 0; l < 2; ++l) {
            int row = ldRow + l * 64;
            As[ldK + 0][row] = pa[l].x; As[ldK + 1][row] = pa[l].y;
            As[ldK + 2][row] = pa[l].z; As[ldK + 3][row] = pa[l].w;
        }
        Bs[ldK + 0][ldRow] = pb.x; Bs[ldK + 1][ldRow] = pb.y;
        Bs[ldK + 2][ldRow] = pb.z; Bs[ldK + 3][ldRow] = pb.w;
        __syncthreads();
        if (kt + 16 < kEnd) loadT(kt + 16);
#pragma unroll
        for (int kk = 0; kk < 16; ++kk) {
            float4 a0 = *(const float4*)&As[kk][ty * 4];
            float4 a1 = *(const float4*)&As[kk][64 + ty * 4];
            float4 b0 = *(const float4*)&Bs[kk][tx * 4];
            float av[8] = {a0.x, a0.y, a0.z, a0.w, a1.x, a1.y, a1.z, a1.w};
            float bv[4] = {b0.x, b0.y, b0.z, b0.w};
#pragma unroll
            for (int i = 0; i < 8; ++i)
#pragma unroll
                for (int j = 0; j < 4; ++j)
                    acc[i][j] = fmaf(av[i], bv[j], acc[i][j]);
        }
    }
    float* outp = out + (long long)blockIdx.z * halfStride + (size_t)wsel * NTOT;
#pragma unroll
    for (int ih = 0; ih < 2; ++ih)
#pragma unroll
        for (int i = 0; i < 4; ++i) {
            int m = mBase + ih * 64 + ty * 4 + i;
            if (m < M) {
                int ai = ih * 4 + i;
                *(float4*)(outp + (size_t)m * 512 + col0 + tx * 4) =
                    make_float4(acc[ai][0], acc[ai][1], acc[ai][2], acc[ai][3]);
            }
        }
}

// ---------------------------------------------------------------------------
// BN stats partials (8-deep batched loads; rowsPerChunk MUST be mult of 8).
// ---------------------------------------------------------------------------
__global__ __launch_bounds__(256) void bnstats_partial_k(
    const float* __restrict__ base0, const float* __restrict__ base1,
    int rowsPerChunk, float* __restrict__ partial, int CT)
{
    int ch = blockIdx.x * 256 + threadIdx.x;
    int tensor = ch >> 9;
    int c = ch & 511;
    const float* p = base0 + (size_t)tensor * NTOT + c;
    const float* q = base1 ? (base1 + (size_t)tensor * NTOT + c) : p;
    float addf = base1 ? 1.f : 0.f;
    int r0 = blockIdx.y * rowsPerChunk;
    float sA = 0.f, sB = 0.f, s2A = 0.f, s2B = 0.f;
    for (int r = 0; r < rowsPerChunk; r += 8) {
        float vv[8];
#pragma unroll
        for (int j = 0; j < 8; ++j) {
            size_t off = (size_t)(r0 + r + j) * 512;
            vv[j] = fmaf(addf, q[off], p[off]);
        }
#pragma unroll
        for (int j = 0; j < 8; j += 2) {
            sA += vv[j];       s2A = fmaf(vv[j], vv[j], s2A);
            sB += vv[j + 1];   s2B = fmaf(vv[j + 1], vv[j + 1], s2B);
        }
    }
    partial[((size_t)blockIdx.y * CT + ch) * 2 + 0] = sA + sB;
    partial[((size_t)blockIdx.y * CT + ch) * 2 + 1] = s2A + s2B;
}

__global__ __launch_bounds__(256) void bnstats_final_k(
    const float* __restrict__ partial, int CT, int chunks,
    const float* __restrict__ gamma, const float* __restrict__ beta,
    float* __restrict__ scale, float* __restrict__ shift)
{
    int ch = blockIdx.x * 256 + threadIdx.x;
    if (ch >= CT) return;
    double s = 0.0, s2 = 0.0;
    for (int k = 0; k < chunks; ++k) {
        s  += (double)partial[((size_t)k * CT + ch) * 2 + 0];
        s2 += (double)partial[((size_t)k * CT + ch) * 2 + 1];
    }
    double mean = s / 4000.0;
    double var = s2 / 4000.0 - mean * mean;
    double sc = (double)gamma[ch] / sqrt(var + 1e-5);
    scale[ch] = (float)sc;
    shift[ch] = (float)((double)beta[ch] - mean * sc);
}

// ---------------------------------------------------------------------------
// Time-segmented BN+LIF. Segment warms up from v=0 at max(0,t0-warm);
// 0.5/step decay + hard resets make the state bit-exact by t0 (see analysis).
// ---------------------------------------------------------------------------
__global__ __launch_bounds__(256) void lif_seg_k(
    const float* __restrict__ p0, const float* __restrict__ p1,
    const float* __restrict__ scale, const float* __restrict__ shift,
    float* __restrict__ out, int useBN, int segLen, int warm)
{
    int gid = blockIdx.x * 256 + threadIdx.x;
    int tensor = gid >> 12;
    int bc = gid & 4095;
    int ch = (tensor << 9) | (bc & 511);
    float sc = useBN ? scale[ch] : 1.f;
    float sh = useBN ? shift[ch] : 0.f;
    const float* q0 = p0 + (size_t)tensor * NTOT + bc;
    const float* q1 = p1 ? (p1 + (size_t)tensor * NTOT + bc) : q0;
    float addf = p1 ? 1.f : 0.f;
    float* o = out + (size_t)tensor * NTOT + bc;
    int t0 = blockIdx.y * segLen;
    int twarm = (t0 - warm > 0) ? (t0 - warm) : 0;
    int tend = (t0 + segLen < TT) ? (t0 + segLen) : TT;
    float v = 0.f;
    float b0[8], b1[8];
#pragma unroll
    for (int j = 0; j < 8; ++j) {
        int tt = twarm + j;
        bool in = tt < tend;
        b0[j] = in ? q0[(size_t)tt * 4096] : 0.f;
        b1[j] = in ? q1[(size_t)tt * 4096] : 0.f;
    }
    for (int t = twarm; t < tend; t += 8) {
        float n0[8], n1[8];
#pragma unroll
        for (int j = 0; j < 8; ++j) {
            int tt = t + 8 + j;
            bool in = tt < tend;
            n0[j] = in ? q0[(size_t)tt * 4096] : 0.f;
            n1[j] = in ? q1[(size_t)tt * 4096] : 0.f;
        }
#pragma unroll
        for (int j = 0; j < 8; ++j) {
            int tc = t + j;
            if (tc >= tend) break;
            float x = fmaf(addf, b1[j], b0[j]);
            float bnx = fmaf(x, sc, sh);
            float h = fmaf(0.5f, v, bnx);
            float s = (h >= 1.f) ? 1.f : 0.f;
            v = (h >= 1.f) ? 0.f : h;
            if (tc >= t0) o[(size_t)tc * 4096] = s;
        }
#pragma unroll
        for (int j = 0; j < 8; ++j) { b0[j] = n0[j]; b1[j] = n1[j]; }
    }
}

// ---------------------------------------------------------------------------
// Segmented depthwise-conv(9) + LIF on v spikes (fused; rolling 16-reg window).
// ---------------------------------------------------------------------------
__global__ __launch_bounds__(256) void dwlif_seg_k(
    const float* __restrict__ vspk, const float* __restrict__ wdw,
    float* __restrict__ out, int segLen, int warm)
{
    int bc = blockIdx.x * 256 + threadIdx.x;   // 0..4095
    int h = (bc >> 6) & 7;
    float w9[9];
#pragma unroll
    for (int j = 0; j < 9; ++j) w9[j] = wdw[h * 9 + j];
    int t0 = blockIdx.y * segLen;
    int twarm = (t0 - warm > 0) ? (t0 - warm) : 0;
    int tend = (t0 + segLen < TT) ? (t0 + segLen) : TT;
    float v = 0.f;
    float win[16];
#pragma unroll
    for (int i = 0; i < 16; ++i) {
        int tt = twarm - 4 + i;
        win[i] = (tt >= 0 && tt < TT) ? vspk[(size_t)tt * 4096 + bc] : 0.f;
    }
    for (int t = twarm; t < tend; t += 8) {
        float pre[8];
#pragma unroll
        for (int i = 0; i < 8; ++i) {
            int tt = t + 12 + i;
            pre[i] = (tt < TT) ? vspk[(size_t)tt * 4096 + bc] : 0.f;
        }
#pragma unroll
        for (int j = 0; j < 8; ++j) {
            int tc = t + j;
            if (tc >= tend) break;
            float x = 0.f;
#pragma unroll
            for (int q = 0; q < 9; ++q)
                x = fmaf(w9[q], win[j + q], x);
            float hh = fmaf(0.5f, v, x);
            float s = (hh >= 1.f) ? 1.f : 0.f;
            v = (hh >= 1.f) ? 0.f : hh;
            if (tc >= t0) out[(size_t)tc * 4096 + bc] = s;
        }
#pragma unroll
        for (int i = 0; i < 8; ++i) win[i] = win[i + 8];
#pragma unroll
        for (int i = 0; i < 8; ++i) win[8 + i] = pre[i];
    }
}

// ---------------------------------------------------------------------------
// Segmented y0 = LIF(g_spk + l_spk + pw-mix(dw_spk)) with fused head mix.
// ---------------------------------------------------------------------------
__global__ __launch_bounds__(256) void y0_seg_k(
    const float* __restrict__ gspk, const float* __restrict__ lspk,
    const float* __restrict__ dwspk, const float* __restrict__ wpw,
    float* __restrict__ out, int segLen, int warm)
{
    int bc = blockIdx.x * 256 + threadIdx.x;   // 0..4095
    int g = (bc >> 6) & 7;
    int d = bc & 63;
    int b512 = bc & ~511;
    float w8[8];
#pragma unroll
    for (int j = 0; j < 8; ++j) w8[j] = wpw[g * 8 + j];
    int t0 = blockIdx.y * segLen;
    int twarm = (t0 - warm > 0) ? (t0 - warm) : 0;
    int tend = (t0 + segLen < TT) ? (t0 + segLen) : TT;
    float v = 0.f;
    size_t tb = (size_t)twarm * 4096;
    float cg = gspk[tb + bc], cl = lspk[tb + bc], cd[8];
#pragma unroll
    for (int j = 0; j < 8; ++j) cd[j] = dwspk[tb + b512 + j * 64 + d];
    for (int t = twarm; t < tend; ++t) {
        float ng = 0.f, nl = 0.f, nd[8] = {};
        if (t + 1 < tend) {
            size_t nb = (size_t)(t + 1) * 4096;
            ng = gspk[nb + bc];
            nl = lspk[nb + bc];
#pragma unroll
            for (int j = 0; j < 8; ++j) nd[j] = dwspk[nb + b512 + j * 64 + d];
        }
        float macc = 0.f;
#pragma unroll
        for (int j = 0; j < 8; ++j) macc = fmaf(w8[j], cd[j], macc);
        float x = (cg + cl) + macc;
        float h = fmaf(0.5f, v, x);
        float s = (h >= 1.f) ? 1.f : 0.f;
        v = (h >= 1.f) ? 0.f : h;
        if (t >= t0) out[(size_t)t * 4096 + bc] = s;
        cg = ng; cl = nl;
#pragma unroll
        for (int j = 0; j < 8; ++j) cd[j] = nd[j];
    }
}

// ---------------------------------------------------------------------------
// KtV partials over t-quarters (exact integer sums), then tiny reduce.
// ---------------------------------------------------------------------------
__global__ __launch_bounds__(256) void ktv_part_k(
    const float* __restrict__ kspk, const float* __restrict__ vspk, float* __restrict__ part)
{
    __shared__ __align__(16) float kb[16][64], vb[16][64];
    int bh = blockIdx.x;
    int seg = blockIdx.y;
    int t0p = seg * 125, t1p = t0p + 125;
    int b = bh >> 3, h = bh & 7;
    int tid = threadIdx.x;
    int d1b = (tid >> 4) * 4, d2b = (tid & 15) * 4;
    size_t cb = (size_t)b * 512 + h * 64;
    float acc[4][4] = {};
    float pk[4], pv[4];
#pragma unroll
    for (int l = 0; l < 4; ++l) {
        int idx = tid + l * 256;
        int tl = idx >> 6, d = idx & 63;
        int t = t0p + tl;
        bool in = t < t1p;
        pk[l] = in ? kspk[(size_t)t * 4096 + cb + d] : 0.f;
        pv[l] = in ? vspk[(size_t)t * 4096 + cb + d] : 0.f;
    }
    for (int tt = t0p; tt < t1p; tt += 16) {
        __syncthreads();
#pragma unroll
        for (int l = 0; l < 4; ++l) {
            int idx = tid + l * 256;
            kb[idx >> 6][idx & 63] = pk[l];
            vb[idx >> 6][idx & 63] = pv[l];
        }
        __syncthreads();
#pragma unroll
        for (int l = 0; l < 4; ++l) {
            int idx = tid + l * 256;
            int tl = idx >> 6, d = idx & 63;
            int t = tt + 16 + tl;
            bool in = t < t1p;
            pk[l] = in ? kspk[(size_t)t * 4096 + cb + d] : 0.f;
            pv[l] = in ? vspk[(size_t)t * 4096 + cb + d] : 0.f;
        }
#pragma unroll
        for (int tl = 0; tl < 16; ++tl) {
            float4 k4 = *(const float4*)&kb[tl][d1b];
            float4 v4 = *(const float4*)&vb[tl][d2b];
            float ka[4] = {k4.x, k4.y, k4.z, k4.w};
            float va[4] = {v4.x, v4.y, v4.z, v4.w};
#pragma unroll
            for (int i = 0; i < 4; ++i)
#pragma unroll
                for (int j = 0; j < 4; ++j)
                    acc[i][j] = fmaf(ka[i], va[j], acc[i][j]);
        }
    }
    size_t ob = ((size_t)seg * 64 + bh) * 4096;
#pragma unroll
    for (int i = 0; i < 4; ++i)
        *(float4*)(part + ob + (size_t)(d1b + i) * 64 + d2b) =
            make_float4(acc[i][0], acc[i][1], acc[i][2], acc[i][3]);
}

__global__ __launch_bounds__(256) void ktv_reduce_k(
    const float* __restrict__ part, float* __restrict__ ktv)
{
    int i4 = (blockIdx.x * 256 + threadIdx.x) * 4;   // 262144 floats
    float4 a = *(const float4*)(part + i4);
    float4 b = *(const float4*)(part + 262144 + i4);
    float4 c = *(const float4*)(part + 2 * 262144 + i4);
    float4 d = *(const float4*)(part + 3 * 262144 + i4);
    *(float4*)(ktv + i4) = make_float4(((a.x + b.x) + c.x) + d.x,
                                       ((a.y + b.y) + c.y) + d.y,
                                       ((a.z + b.z) + c.z) + d.z,
                                       ((a.w + b.w) + c.w) + d.w);
}

// ---------------------------------------------------------------------------
// Global attention apply: g_pre = gscale * q · ktv
// ---------------------------------------------------------------------------
__global__ __launch_bounds__(256) void gapply_k(
    const float* __restrict__ qspk, const float* __restrict__ ktv,
    float* __restrict__ gpre, float gscale)
{
    __shared__ float qrow[512];
    int t = blockIdx.x, b = blockIdx.y;
    int tid = threadIdx.x;
    size_t rbase = (size_t)t * 4096 + (size_t)b * 512;
    qrow[tid] = qspk[rbase + tid];
    qrow[tid + 256] = qspk[rbase + tid + 256];
    __syncthreads();
#pragma unroll
    for (int oi = 0; oi < 2; ++oi) {
        int c = tid + oi * 256;
        int h = c >> 6, d2 = c & 63;
        const float* kt = ktv + ((size_t)(b * 8 + h) * 64) * 64 + d2;
        const float* qr = qrow + h * 64;
        float acc = 0.f;
#pragma unroll
        for (int d1 = 0; d1 < 64; ++d1)
            acc = fmaf(qr[d1], kt[(size_t)d1 * 64], acc);
        gpre[rbase + c] = acc * gscale;
    }
}

// ---------------------------------------------------------------------------
// Local banded attention.
// ---------------------------------------------------------------------------
__global__ __launch_bounds__(256) void local_k(
    const float* __restrict__ qspk, const float* __restrict__ kspk,
    const float* __restrict__ vspk, float* __restrict__ lpre, float lscale)
{
    __shared__ __align__(16) float qs[32][64];
    __shared__ __align__(16) float ks[72][64];
    __shared__ __align__(16) float vs[72][64];
    __shared__ float sm[32][72];
    int t0 = blockIdx.x * 32;
    int bh = blockIdx.y;
    int b = bh >> 3, h = bh & 7;
    int tid = threadIdx.x;
    size_t cb = (size_t)b * 512 + h * 64;

    for (int idx = tid; idx < 2048; idx += 256) {
        int tl = idx >> 6, d = idx & 63;
        int t = t0 + tl;
        qs[tl][d] = (t < TT) ? qspk[(size_t)t * 4096 + cb + d] : 0.f;
    }
    for (int idx = tid; idx < 4608; idx += 256) {
        int ul = idx >> 6, d = idx & 63;
        int u = t0 - WW + ul;
        bool in = (u >= 0 && u < TT);
        ks[ul][d] = in ? kspk[(size_t)u * 4096 + cb + d] : 0.f;
        vs[ul][d] = in ? vspk[(size_t)u * 4096 + cb + d] : 0.f;
    }
    __syncthreads();

    int tA = tid >> 3;
    int ug = tid & 7;
    float4 qreg[16];
#pragma unroll
    for (int i = 0; i < 16; ++i) qreg[i] = *(const float4*)&qs[tA][i * 4];
#pragma unroll
    for (int ui = 0; ui < 9; ++ui) {
        int u = ug + ui * 8;
        float acc = 0.f;
#pragma unroll
        for (int i = 0; i < 16; ++i) {
            float4 k4 = *(const float4*)&ks[u][i * 4];
            acc = fmaf(qreg[i].x, k4.x, acc);
            acc = fmaf(qreg[i].y, k4.y, acc);
            acc = fmaf(qreg[i].z, k4.z, acc);
            acc = fmaf(qreg[i].w, k4.w, acc);
        }
        sm[tA][u] = acc;
    }
    __syncthreads();

#pragma unroll
    for (int oi = 0; oi < 2; ++oi) {
        int idx = tid + oi * 256;
        int t = idx >> 4;
        int dg = (idx & 15) * 4;
        float4 acc = make_float4(0.f, 0.f, 0.f, 0.f);
        for (int o = 0; o < 41; ++o) {
            int u = t + o;
            float s = sm[t][u];
            float4 v4 = *(const float4*)&vs[u][dg];
            acc.x = fmaf(s, v4.x, acc.x);
            acc.y = fmaf(s, v4.y, acc.y);
            acc.z = fmaf(s, v4.z, acc.z);
            acc.w = fmaf(s, v4.w, acc.w);
        }
        int tg = t0 + t;
        if (tg < TT) {
            acc.x *= lscale; acc.y *= lscale; acc.z *= lscale; acc.w *= lscale;
            *(float4*)(lpre + (size_t)tg * 4096 + cb + dg) = acc;
        }
    }
}

// ---------------------------------------------------------------------------
extern "C" void kernel_launch(void* const* d_in, const int* in_sizes, int n_in,
                              void* d_out, int out_size, void* d_ws, size_t ws_size,
                              hipStream_t stream)
{
    const float* x       = (const float*)d_in[0];
    const float* wq      = (const float*)d_in[1];
    const float* wk      = (const float*)d_in[2];
    const float* wv      = (const float*)d_in[3];
    const float* w_mattn = (const float*)d_in[4];
    const float* w_proj  = (const float*)d_in[5];
    const float* w_dw    = (const float*)d_in[6];
    const float* w_pw    = (const float*)d_in[7];
    const float* bn_g    = (const float*)d_in[8];
    const float* bn_b    = (const float*)d_in[9];
    float* out = (float*)d_out;
    float* ws = (float*)d_ws;

    float gs32 = (float)std::sqrt((double)(64 * 500));
    float gscale = (float)(1.0 / (double)gs32);
    float ls32 = (float)std::sqrt((double)(64 * 41));
    float lscale = (float)(1.0 / (double)ls32);
    const int M = TT * 8;   // 4000

    auto S = [&](int i) { return ws + (size_t)i * NTOT; };
    float* ktvBuf  = ws + (size_t)9 * NTOT;   // 262144
    float* partial = ktvBuf + 262144;         // <=61440
    float* sc_qkv  = partial + 61440;
    float* sh_qkv  = sc_qkv + 1536;
    float* sc_m    = sh_qkv + 1536;
    float* sh_m    = sc_m + 512;
    float* sc_p    = sh_m + 512;
    float* sh_p    = sc_p + 512;

    // 1) QKV GEMM (full K, balanced 768 blocks) -> pre S0,S1,S2
    gemm_k<<<dim3(32, 24, 1), 256, 0, stream>>>(x, wq, wk, wv, S(0), M, 512, 0);
    // 2) BN stats (rowsPerChunk 200: multiple of 8)
    bnstats_partial_k<<<dim3(6, 20), 256, 0, stream>>>(S(0), nullptr, 200, partial, 1536);
    bnstats_final_k<<<6, 256, 0, stream>>>(partial, 1536, 20, bn_g, bn_b, sc_qkv, sh_qkv);
    // 3) segmented BN+LIF -> q,k,v spikes S3,S4,S5
    lif_seg_k<<<dim3(48, 5), 256, 0, stream>>>(S(0), nullptr, sc_qkv, sh_qkv, S(3), 1, 100, 64);
    // 4) global branch: KtV partials (S6 scratch) -> reduce -> apply
    ktv_part_k<<<dim3(64, 4), 256, 0, stream>>>(S(4), S(5), S(6));
    ktv_reduce_k<<<256, 256, 0, stream>>>(S(6), ktvBuf);
    gapply_k<<<dim3(500, 8), 256, 0, stream>>>(S(3), ktvBuf, S(0), gscale);        // g_pre -> S0
    // 5) local banded attention -> l_pre S1
    local_k<<<dim3(16, 64), 256, 0, stream>>>(S(3), S(4), S(5), S(1), lscale);
    // 6) g,l LIF (2 tensors S0,S1 -> spikes S2,S3); dw conv+LIF fused (S5 -> S4)
    lif_seg_k<<<dim3(32, 5), 256, 0, stream>>>(S(0), nullptr, nullptr, nullptr, S(2), 0, 100, 64);
    dwlif_seg_k<<<dim3(16, 5), 256, 0, stream>>>(S(5), w_dw, S(4), 100, 64);
    // 7) y0 = LIF(g+l+mix(dw)) -> S6
    y0_seg_k<<<dim3(16, 16), 256, 0, stream>>>(S(2), S(3), S(4), w_pw, S(6), 32, 64);
    // 8) mattn GEMM (split-K=2) -> S7,S8; BN; LIF -> y1 S0
    gemm_k<<<dim3(32, 8, 2), 256, 0, stream>>>(S(6), w_mattn, w_mattn, w_mattn, S(7), M, 256, (long long)NTOT);
    bnstats_partial_k<<<dim3(2, 20), 256, 0, stream>>>(S(7), S(8), 200, partial, 512);
    bnstats_final_k<<<2, 256, 0, stream>>>(partial, 512, 20, bn_g + 1536, bn_b + 1536, sc_m, sh_m);
    lif_seg_k<<<dim3(16, 16), 256, 0, stream>>>(S(7), S(8), sc_m, sh_m, S(0), 1, 32, 64);
    // 9) proj GEMM (split-K=2) -> S1,S2; BN; LIF -> out
    gemm_k<<<dim3(32, 8, 2), 256, 0, stream>>>(S(0), w_proj, w_proj, w_proj, S(1), M, 256, (long long)NTOT);
    bnstats_partial_k<<<dim3(2, 20), 256, 0, stream>>>(S(1), S(2), 200, partial, 512);
    bnstats_final_k<<<2, 256, 0, stream>>>(partial, 512, 20, bn_g + 2048, bn_b + 2048, sc_p, sh_p);
    lif_seg_k<<<dim3(16, 16), 256, 0, stream>>>(S(1), S(2), sc_p, sh_p, out, 1, 32, 64);

    (void)in_sizes; (void)n_in; (void)out_size; (void)ws_size;
}

// Round 5
// 473.027 us; speedup vs baseline: 1.9612x; 1.0577x over previous
//
#include <hip/hip_runtime.h>
#include <cmath>

#define TT 500
#define NTOT 2048000       // T*B*C elements
#define WW 20

// ---------------------------------------------------------------------------
// QKV GEMM: A fp32 [M,512], 3 weight tensors. BM=128,BN=64,BK=32, 8x4 tile.
// Fused per-block column stats (sum, sumsq over the block's 128 rows).
// ---------------------------------------------------------------------------
__global__ __launch_bounds__(256) void gemm_f_k(
    const float* __restrict__ A,
    const float* __restrict__ W0, const float* __restrict__ W1, const float* __restrict__ W2,
    float* __restrict__ out, float* __restrict__ colpart, int M)
{
    __shared__ __align__(16) float As[32][132];
    __shared__ __align__(16) float Bs[32][68];
    __shared__ float red[16][64][2];
    int tid = threadIdx.x;
    int mBase = blockIdx.x * 128;
    int nBase = blockIdx.y * 64;
    int wsel = nBase >> 9;
    const float* Wp = (wsel == 0) ? W0 : ((wsel == 1) ? W1 : W2);
    int col0 = nBase & 511;
    int ty = tid >> 4, tx = tid & 15;
    int aRow = tid >> 1, aK = (tid & 1) * 16;
    int bRow = tid >> 2, bK = (tid & 3) * 8;
    float acc[8][4] = {};
    float4 pa[4], pb[2];

    auto loadT = [&](int kt) {
        int m = mBase + aRow;
        if (m < M) {
            const float* ap = A + (size_t)m * 512 + kt + aK;
            pa[0] = ((const float4*)ap)[0]; pa[1] = ((const float4*)ap)[1];
            pa[2] = ((const float4*)ap)[2]; pa[3] = ((const float4*)ap)[3];
        } else {
            pa[0] = pa[1] = pa[2] = pa[3] = make_float4(0.f, 0.f, 0.f, 0.f);
        }
        const float* bp = Wp + (size_t)(col0 + bRow) * 512 + kt + bK;
        pb[0] = ((const float4*)bp)[0]; pb[1] = ((const float4*)bp)[1];
    };
    loadT(0);
    for (int kt = 0; kt < 512; kt += 32) {
        __syncthreads();
#pragma unroll
        for (int q = 0; q < 4; ++q) {
            As[aK + q * 4 + 0][aRow] = pa[q].x; As[aK + q * 4 + 1][aRow] = pa[q].y;
            As[aK + q * 4 + 2][aRow] = pa[q].z; As[aK + q * 4 + 3][aRow] = pa[q].w;
        }
#pragma unroll
        for (int q = 0; q < 2; ++q) {
            Bs[bK + q * 4 + 0][bRow] = pb[q].x; Bs[bK + q * 4 + 1][bRow] = pb[q].y;
            Bs[bK + q * 4 + 2][bRow] = pb[q].z; Bs[bK + q * 4 + 3][bRow] = pb[q].w;
        }
        __syncthreads();
        if (kt + 32 < 512) loadT(kt + 32);
#pragma unroll
        for (int kk = 0; kk < 32; ++kk) {
            float4 a0 = *(const float4*)&As[kk][ty * 4];
            float4 a1 = *(const float4*)&As[kk][64 + ty * 4];
            float4 b0 = *(const float4*)&Bs[kk][tx * 4];
            float av[8] = {a0.x, a0.y, a0.z, a0.w, a1.x, a1.y, a1.z, a1.w};
            float bv[4] = {b0.x, b0.y, b0.z, b0.w};
#pragma unroll
            for (int i = 0; i < 8; ++i)
#pragma unroll
                for (int j = 0; j < 4; ++j)
                    acc[i][j] = fmaf(av[i], bv[j], acc[i][j]);
        }
    }
    // fused column stats over this block's 128 rows (pad rows are exact 0)
#pragma unroll
    for (int j = 0; j < 4; ++j) {
        float s = 0.f, q = 0.f;
#pragma unroll
        for (int i = 0; i < 8; ++i) { s += acc[i][j]; q = fmaf(acc[i][j], acc[i][j], q); }
        red[ty][tx * 4 + j][0] = s;
        red[ty][tx * 4 + j][1] = q;
    }
    __syncthreads();
    if (tid < 64) {
        float ss = 0.f, qq = 0.f;
#pragma unroll
        for (int r = 0; r < 16; ++r) { ss += red[r][tid][0]; qq += red[r][tid][1]; }
        int gcol = wsel * 512 + col0 + tid;
        colpart[((size_t)blockIdx.x * 1536 + gcol) * 2 + 0] = ss;
        colpart[((size_t)blockIdx.x * 1536 + gcol) * 2 + 1] = qq;
    }
    float* outp = out + (size_t)wsel * NTOT;
#pragma unroll
    for (int ih = 0; ih < 2; ++ih)
#pragma unroll
        for (int i = 0; i < 4; ++i) {
            int m = mBase + ih * 64 + ty * 4 + i;
            if (m < M) {
                int ai = ih * 4 + i;
                *(float4*)(outp + (size_t)m * 512 + col0 + tx * 4) =
                    make_float4(acc[ai][0], acc[ai][1], acc[ai][2], acc[ai][3]);
            }
        }
}

// ---------------------------------------------------------------------------
// Spike-input GEMM: A uchar [M,512], one weight. BM=64,BN=64,BK=32, 4x4 tile.
// Fused column stats. Grid (63, 8) = 504 blocks.
// ---------------------------------------------------------------------------
__global__ __launch_bounds__(256) void gemm_b_k(
    const unsigned char* __restrict__ A, const float* __restrict__ W,
    float* __restrict__ out, float* __restrict__ colpart, int M)
{
    __shared__ __align__(16) float As[32][68];
    __shared__ __align__(16) float Bs[32][68];
    __shared__ float red[16][64][2];
    int tid = threadIdx.x;
    int mBase = blockIdx.x * 64;
    int col0 = blockIdx.y * 64;
    int ty = tid >> 4, tx = tid & 15;
    int sRow = tid >> 2, sK = (tid & 3) * 8;
    float acc[4][4] = {};
    uchar4 pa[2];
    float4 pb[2];

    auto loadT = [&](int kt) {
        int m = mBase + sRow;
        if (m < M) {
            const unsigned char* ap = A + (size_t)m * 512 + kt + sK;
            pa[0] = *(const uchar4*)(ap);
            pa[1] = *(const uchar4*)(ap + 4);
        } else {
            pa[0] = make_uchar4(0, 0, 0, 0); pa[1] = make_uchar4(0, 0, 0, 0);
        }
        const float* bp = W + (size_t)(col0 + sRow) * 512 + kt + sK;
        pb[0] = ((const float4*)bp)[0]; pb[1] = ((const float4*)bp)[1];
    };
    loadT(0);
    for (int kt = 0; kt < 512; kt += 32) {
        __syncthreads();
        As[sK + 0][sRow] = (float)pa[0].x; As[sK + 1][sRow] = (float)pa[0].y;
        As[sK + 2][sRow] = (float)pa[0].z; As[sK + 3][sRow] = (float)pa[0].w;
        As[sK + 4][sRow] = (float)pa[1].x; As[sK + 5][sRow] = (float)pa[1].y;
        As[sK + 6][sRow] = (float)pa[1].z; As[sK + 7][sRow] = (float)pa[1].w;
#pragma unroll
        for (int q = 0; q < 2; ++q) {
            Bs[sK + q * 4 + 0][sRow] = pb[q].x; Bs[sK + q * 4 + 1][sRow] = pb[q].y;
            Bs[sK + q * 4 + 2][sRow] = pb[q].z; Bs[sK + q * 4 + 3][sRow] = pb[q].w;
        }
        __syncthreads();
        if (kt + 32 < 512) loadT(kt + 32);
#pragma unroll
        for (int kk = 0; kk < 32; ++kk) {
            float4 a0 = *(const float4*)&As[kk][ty * 4];
            float4 b0 = *(const float4*)&Bs[kk][tx * 4];
            float av[4] = {a0.x, a0.y, a0.z, a0.w};
            float bv[4] = {b0.x, b0.y, b0.z, b0.w};
#pragma unroll
            for (int i = 0; i < 4; ++i)
#pragma unroll
                for (int j = 0; j < 4; ++j)
                    acc[i][j] = fmaf(av[i], bv[j], acc[i][j]);
        }
    }
#pragma unroll
    for (int j = 0; j < 4; ++j) {
        float s = 0.f, q = 0.f;
#pragma unroll
        for (int i = 0; i < 4; ++i) { s += acc[i][j]; q = fmaf(acc[i][j], acc[i][j], q); }
        red[ty][tx * 4 + j][0] = s;
        red[ty][tx * 4 + j][1] = q;
    }
    __syncthreads();
    if (tid < 64) {
        float ss = 0.f, qq = 0.f;
#pragma unroll
        for (int r = 0; r < 16; ++r) { ss += red[r][tid][0]; qq += red[r][tid][1]; }
        int gcol = col0 + tid;
        colpart[((size_t)blockIdx.x * 512 + gcol) * 2 + 0] = ss;
        colpart[((size_t)blockIdx.x * 512 + gcol) * 2 + 1] = qq;
    }
#pragma unroll
    for (int i = 0; i < 4; ++i) {
        int m = mBase + ty * 4 + i;
        if (m < M)
            *(float4*)(out + (size_t)m * 512 + col0 + tx * 4) =
                make_float4(acc[i][0], acc[i][1], acc[i][2], acc[i][3]);
    }
}

// ---------------------------------------------------------------------------
// BN finalize: reduce chunked column partials in f64 -> scale/shift.
// ---------------------------------------------------------------------------
__global__ __launch_bounds__(256) void bnstats_final_k(
    const float* __restrict__ partial, int CT, int chunks,
    const float* __restrict__ gamma, const float* __restrict__ beta,
    float* __restrict__ scale, float* __restrict__ shift)
{
    int ch = blockIdx.x * 256 + threadIdx.x;
    if (ch >= CT) return;
    double s = 0.0, s2 = 0.0;
    for (int k = 0; k < chunks; ++k) {
        s  += (double)partial[((size_t)k * CT + ch) * 2 + 0];
        s2 += (double)partial[((size_t)k * CT + ch) * 2 + 1];
    }
    double mean = s / 4000.0;
    double var = s2 / 4000.0 - mean * mean;
    double sc = (double)gamma[ch] / sqrt(var + 1e-5);
    scale[ch] = (float)sc;
    shift[ch] = (float)((double)beta[ch] - mean * sc);
}

// ---------------------------------------------------------------------------
// Time-segmented BN+LIF; fp32 in, byte or fp32 spikes out. 8-deep prefetch.
// ---------------------------------------------------------------------------
__global__ __launch_bounds__(256) void lif_seg_k(
    const float* __restrict__ pre, const float* __restrict__ scale,
    const float* __restrict__ shift, float* __restrict__ outF,
    unsigned char* __restrict__ outB, int segLen, int warm)
{
    int gid = blockIdx.x * 256 + threadIdx.x;
    int tensor = gid >> 12;
    int bc = gid & 4095;
    int ch = (tensor << 9) | (bc & 511);
    float sc = scale[ch];
    float sh = shift[ch];
    const float* q0 = pre + (size_t)tensor * NTOT + bc;
    float* oF = outF ? outF + (size_t)tensor * NTOT + bc : nullptr;
    unsigned char* oB = outB ? outB + (size_t)tensor * NTOT + bc : nullptr;
    int t0 = blockIdx.y * segLen;
    int twarm = (t0 - warm > 0) ? (t0 - warm) : 0;
    int tend = (t0 + segLen < TT) ? (t0 + segLen) : TT;
    float v = 0.f;
    float b0[8];
#pragma unroll
    for (int j = 0; j < 8; ++j) {
        int tt = twarm + j;
        b0[j] = (tt < tend) ? q0[(size_t)tt * 4096] : 0.f;
    }
    for (int t = twarm; t < tend; t += 8) {
        float n0[8];
#pragma unroll
        for (int j = 0; j < 8; ++j) {
            int tt = t + 8 + j;
            n0[j] = (tt < tend) ? q0[(size_t)tt * 4096] : 0.f;
        }
#pragma unroll
        for (int j = 0; j < 8; ++j) {
            int tc = t + j;
            if (tc >= tend) break;
            float bnx = fmaf(b0[j], sc, sh);
            float h = fmaf(0.5f, v, bnx);
            float s = (h >= 1.f) ? 1.f : 0.f;
            v = (h >= 1.f) ? 0.f : h;
            if (tc >= t0) {
                if (oB) oB[(size_t)tc * 4096] = (unsigned char)s;
                else    oF[(size_t)tc * 4096] = s;
            }
        }
#pragma unroll
        for (int j = 0; j < 8; ++j) b0[j] = n0[j];
    }
}

// ---------------------------------------------------------------------------
// KtV partials over t-quarters from byte spikes (exact integer sums).
// ---------------------------------------------------------------------------
__global__ __launch_bounds__(256) void ktv_part_k(
    const unsigned char* __restrict__ kspk, const unsigned char* __restrict__ vspk,
    float* __restrict__ part)
{
    __shared__ __align__(16) float kb[16][64], vb[16][64];
    int bh = blockIdx.x;
    int seg = blockIdx.y;
    int t0p = seg * 125, t1p = t0p + 125;
    int b = bh >> 3, h = bh & 7;
    int tid = threadIdx.x;
    int d1b = (tid >> 4) * 4, d2b = (tid & 15) * 4;
    size_t cb = (size_t)b * 512 + h * 64;
    int sRow = tid >> 4;
    int sD = (tid & 15) * 4;
    float acc[4][4] = {};
    uchar4 pk, pv;
    auto preload = [&](int tt) {
        int t = tt + sRow;
        if (t < t1p) {
            pk = *(const uchar4*)(kspk + (size_t)t * 4096 + cb + sD);
            pv = *(const uchar4*)(vspk + (size_t)t * 4096 + cb + sD);
        } else {
            pk = make_uchar4(0, 0, 0, 0); pv = make_uchar4(0, 0, 0, 0);
        }
    };
    preload(t0p);
    for (int tt = t0p; tt < t1p; tt += 16) {
        __syncthreads();
        kb[sRow][sD + 0] = (float)pk.x; kb[sRow][sD + 1] = (float)pk.y;
        kb[sRow][sD + 2] = (float)pk.z; kb[sRow][sD + 3] = (float)pk.w;
        vb[sRow][sD + 0] = (float)pv.x; vb[sRow][sD + 1] = (float)pv.y;
        vb[sRow][sD + 2] = (float)pv.z; vb[sRow][sD + 3] = (float)pv.w;
        __syncthreads();
        preload(tt + 16);
#pragma unroll
        for (int tl = 0; tl < 16; ++tl) {
            float4 k4 = *(const float4*)&kb[tl][d1b];
            float4 v4 = *(const float4*)&vb[tl][d2b];
            float ka[4] = {k4.x, k4.y, k4.z, k4.w};
            float va[4] = {v4.x, v4.y, v4.z, v4.w};
#pragma unroll
            for (int i = 0; i < 4; ++i)
#pragma unroll
                for (int j = 0; j < 4; ++j)
                    acc[i][j] = fmaf(ka[i], va[j], acc[i][j]);
        }
    }
    size_t ob = ((size_t)seg * 64 + bh) * 4096;
#pragma unroll
    for (int i = 0; i < 4; ++i)
        *(float4*)(part + ob + (size_t)(d1b + i) * 64 + d2b) =
            make_float4(acc[i][0], acc[i][1], acc[i][2], acc[i][3]);
}

__global__ __launch_bounds__(256) void ktv_reduce_k(
    const float* __restrict__ part, float* __restrict__ ktv)
{
    int i4 = (blockIdx.x * 256 + threadIdx.x) * 4;
    float4 a = *(const float4*)(part + i4);
    float4 b = *(const float4*)(part + 262144 + i4);
    float4 c = *(const float4*)(part + 2 * 262144 + i4);
    float4 d = *(const float4*)(part + 3 * 262144 + i4);
    *(float4*)(ktv + i4) = make_float4(((a.x + b.x) + c.x) + d.x,
                                       ((a.y + b.y) + c.y) + d.y,
                                       ((a.z + b.z) + c.z) + d.z,
                                       ((a.w + b.w) + c.w) + d.w);
}

// ---------------------------------------------------------------------------
// Global attention apply, t-tiled x10: g_pre = gscale * q . ktv. Grid (50, 8).
// ---------------------------------------------------------------------------
__global__ __launch_bounds__(256) void gapply_t_k(
    const unsigned char* __restrict__ sq, const float* __restrict__ ktv,
    float* __restrict__ gpre, float gscale)
{
    __shared__ float qs[10][512];
    int tid = threadIdx.x;
    int t0 = blockIdx.x * 10;
    int b = blockIdx.y;
    for (int i = tid; i < 1280; i += 256) {
        int t = i >> 7;
        int c4 = (i & 127) * 4;
        uchar4 u = *(const uchar4*)(sq + (size_t)(t0 + t) * 4096 + b * 512 + c4);
        qs[t][c4 + 0] = (float)u.x; qs[t][c4 + 1] = (float)u.y;
        qs[t][c4 + 2] = (float)u.z; qs[t][c4 + 3] = (float)u.w;
    }
    __syncthreads();
#pragma unroll
    for (int half = 0; half < 2; ++half) {
        int c = tid + half * 256;
        int h = c >> 6, dcol = c & 63;
        const float* kt = ktv + ((size_t)(b * 8 + h) * 64) * 64 + dcol;
        float acc[10] = {};
        for (int d1 = 0; d1 < 64; ++d1) {
            float kv = kt[(size_t)d1 * 64];
#pragma unroll
            for (int t = 0; t < 10; ++t)
                acc[t] = fmaf(qs[t][h * 64 + d1], kv, acc[t]);
        }
#pragma unroll
        for (int t = 0; t < 10; ++t)
            gpre[(size_t)(t0 + t) * 4096 + b * 512 + c] = acc[t] * gscale;
    }
}

// ---------------------------------------------------------------------------
// Local banded attention from byte spikes.
// ---------------------------------------------------------------------------
__global__ __launch_bounds__(256) void local_k(
    const unsigned char* __restrict__ qspk, const unsigned char* __restrict__ kspk,
    const unsigned char* __restrict__ vspk, float* __restrict__ lpre, float lscale)
{
    __shared__ __align__(16) float qs[32][64];
    __shared__ __align__(16) float ks[72][64];
    __shared__ __align__(16) float vs[72][64];
    __shared__ float sm[32][72];
    int t0 = blockIdx.x * 32;
    int bh = blockIdx.y;
    int b = bh >> 3, h = bh & 7;
    int tid = threadIdx.x;
    size_t cb = (size_t)b * 512 + h * 64;

    for (int i = tid; i < 512; i += 256) {
        int r = i >> 4, d4 = (i & 15) * 4;
        int t = t0 + r;
        if (t < TT) {
            uchar4 u = *(const uchar4*)(qspk + (size_t)t * 4096 + cb + d4);
            qs[r][d4 + 0] = (float)u.x; qs[r][d4 + 1] = (float)u.y;
            qs[r][d4 + 2] = (float)u.z; qs[r][d4 + 3] = (float)u.w;
        } else {
            qs[r][d4 + 0] = 0.f; qs[r][d4 + 1] = 0.f; qs[r][d4 + 2] = 0.f; qs[r][d4 + 3] = 0.f;
        }
    }
    for (int i = tid; i < 1152; i += 256) {
        int r = i >> 4, d4 = (i & 15) * 4;
        int u_ = t0 - WW + r;
        if (u_ >= 0 && u_ < TT) {
            uchar4 uk = *(const uchar4*)(kspk + (size_t)u_ * 4096 + cb + d4);
            uchar4 uv = *(const uchar4*)(vspk + (size_t)u_ * 4096 + cb + d4);
            ks[r][d4 + 0] = (float)uk.x; ks[r][d4 + 1] = (float)uk.y;
            ks[r][d4 + 2] = (float)uk.z; ks[r][d4 + 3] = (float)uk.w;
            vs[r][d4 + 0] = (float)uv.x; vs[r][d4 + 1] = (float)uv.y;
            vs[r][d4 + 2] = (float)uv.z; vs[r][d4 + 3] = (float)uv.w;
        } else {
            ks[r][d4 + 0] = 0.f; ks[r][d4 + 1] = 0.f; ks[r][d4 + 2] = 0.f; ks[r][d4 + 3] = 0.f;
            vs[r][d4 + 0] = 0.f; vs[r][d4 + 1] = 0.f; vs[r][d4 + 2] = 0.f; vs[r][d4 + 3] = 0.f;
        }
    }
    __syncthreads();

    int tA = tid >> 3;
    int ug = tid & 7;
    float4 qreg[16];
#pragma unroll
    for (int i = 0; i < 16; ++i) qreg[i] = *(const float4*)&qs[tA][i * 4];
#pragma unroll
    for (int ui = 0; ui < 9; ++ui) {
        int u = ug + ui * 8;
        float acc = 0.f;
#pragma unroll
        for (int i = 0; i < 16; ++i) {
            float4 k4 = *(const float4*)&ks[u][i * 4];
            acc = fmaf(qreg[i].x, k4.x, acc);
            acc = fmaf(qreg[i].y, k4.y, acc);
            acc = fmaf(qreg[i].z, k4.z, acc);
            acc = fmaf(qreg[i].w, k4.w, acc);
        }
        sm[tA][u] = acc;
    }
    __syncthreads();

#pragma unroll
    for (int oi = 0; oi < 2; ++oi) {
        int idx = tid + oi * 256;
        int t = idx >> 4;
        int dg = (idx & 15) * 4;
        float4 acc = make_float4(0.f, 0.f, 0.f, 0.f);
        for (int o = 0; o < 41; ++o) {
            int u = t + o;
            float s = sm[t][u];
            float4 v4 = *(const float4*)&vs[u][dg];
            acc.x = fmaf(s, v4.x, acc.x);
            acc.y = fmaf(s, v4.y, acc.y);
            acc.z = fmaf(s, v4.z, acc.z);
            acc.w = fmaf(s, v4.w, acc.w);
        }
        int tg = t0 + t;
        if (tg < TT) {
            acc.x *= lscale; acc.y *= lscale; acc.z *= lscale; acc.w *= lscale;
            *(float4*)(lpre + (size_t)tg * 4096 + cb + dg) = acc;
        }
    }
}

// ---------------------------------------------------------------------------
// Fused branch kernel: g-LIF + l-LIF + dwconv9-LIF + head-mix (wave shfl) +
// y0-LIF. One lane per channel; lane = h*8+dl so the mix is 8 shuffles.
// Grid (16, nseg), block 256 (4 waves; wave -> (b, dgroup)).
// ---------------------------------------------------------------------------
__global__ __launch_bounds__(256) void branch_y0_k(
    const float* __restrict__ gpre, const float* __restrict__ lpre,
    const unsigned char* __restrict__ sv, const float* __restrict__ wdw,
    const float* __restrict__ wpw, unsigned char* __restrict__ sy0,
    int segLen, int warm)
{
    int tid = threadIdx.x;
    int wave = tid >> 6, lane = tid & 63;
    int gw = blockIdx.x * 4 + wave;    // 0..63
    int b = gw >> 3, dg = gw & 7;
    int h = lane >> 3, dl = lane & 7;
    int c = h * 64 + dg * 8 + dl;
    int base = b * 512 + c;
    float w9[9];
#pragma unroll
    for (int j = 0; j < 9; ++j) w9[j] = wdw[h * 9 + j];
    float w8[8];
#pragma unroll
    for (int j = 0; j < 8; ++j) w8[j] = wpw[h * 8 + j];
    int t0 = blockIdx.y * segLen;
    int twarm = (t0 - warm > 0) ? (t0 - warm) : 0;
    int tend = (t0 + segLen < TT) ? (t0 + segLen) : TT;
    float vg = 0.f, vl = 0.f, vd = 0.f, vy = 0.f;
    float win[12];
#pragma unroll
    for (int i = 0; i < 12; ++i) {
        int tt = twarm - 4 + i;
        win[i] = (tt >= 0 && tt < TT) ? (float)sv[(size_t)tt * 4096 + base] : 0.f;
    }
    float pg[4], pl[4], pv[4];
    auto pref = [&](int t) {
#pragma unroll
        for (int j = 0; j < 4; ++j) {
            int tt = t + j;
            bool in = tt < tend;
            pg[j] = in ? gpre[(size_t)tt * 4096 + base] : 0.f;
            pl[j] = in ? lpre[(size_t)tt * 4096 + base] : 0.f;
            int tv = t + 8 + j;
            pv[j] = (tv < TT) ? (float)sv[(size_t)tv * 4096 + base] : 0.f;
        }
    };
    pref(twarm);
    for (int t = twarm; t < tend; t += 4) {
        float cg[4], cl[4], cv[4];
#pragma unroll
        for (int j = 0; j < 4; ++j) { cg[j] = pg[j]; cl[j] = pl[j]; cv[j] = pv[j]; }
        pref(t + 4);
#pragma unroll
        for (int j = 0; j < 4; ++j) {
            int tc = t + j;
            if (tc >= tend) break;
            float x = 0.f;
#pragma unroll
            for (int q = 0; q < 9; ++q) x = fmaf(w9[q], win[j + q], x);
            float hd = fmaf(0.5f, vd, x);
            float sd = (hd >= 1.f) ? 1.f : 0.f;
            vd = (hd >= 1.f) ? 0.f : hd;
            float hg = fmaf(0.5f, vg, cg[j]);
            float sg = (hg >= 1.f) ? 1.f : 0.f;
            vg = (hg >= 1.f) ? 0.f : hg;
            float hl = fmaf(0.5f, vl, cl[j]);
            float sl = (hl >= 1.f) ? 1.f : 0.f;
            vl = (hl >= 1.f) ? 0.f : hl;
            float mix = 0.f;
#pragma unroll
            for (int h2 = 0; h2 < 8; ++h2)
                mix = fmaf(w8[h2], __shfl(sd, h2 * 8 + dl, 64), mix);
            float xy = (sg + sl) + mix;
            float hy = fmaf(0.5f, vy, xy);
            float sy = (hy >= 1.f) ? 1.f : 0.f;
            vy = (hy >= 1.f) ? 0.f : hy;
            if (tc >= t0) sy0[(size_t)tc * 4096 + base] = (unsigned char)sy;
        }
#pragma unroll
        for (int i = 0; i < 8; ++i) win[i] = win[i + 4];
#pragma unroll
        for (int i = 0; i < 4; ++i) win[8 + i] = cv[i];
    }
}

// ---------------------------------------------------------------------------
extern "C" void kernel_launch(void* const* d_in, const int* in_sizes, int n_in,
                              void* d_out, int out_size, void* d_ws, size_t ws_size,
                              hipStream_t stream)
{
    const float* x       = (const float*)d_in[0];
    const float* wq      = (const float*)d_in[1];
    const float* wk      = (const float*)d_in[2];
    const float* wv      = (const float*)d_in[3];
    const float* w_mattn = (const float*)d_in[4];
    const float* w_proj  = (const float*)d_in[5];
    const float* w_dw    = (const float*)d_in[6];
    const float* w_pw    = (const float*)d_in[7];
    const float* bn_g    = (const float*)d_in[8];
    const float* bn_b    = (const float*)d_in[9];
    float* out = (float*)d_out;
    float* ws = (float*)d_ws;

    float gs32 = (float)std::sqrt((double)(64 * 500));
    float gscale = (float)(1.0 / (double)gs32);
    float ls32 = (float)std::sqrt((double)(64 * 41));
    float lscale = (float)(1.0 / (double)ls32);
    const int M = TT * 8;   // 4000

    float* S0 = ws;
    float* S1 = ws + (size_t)NTOT;
    float* S2 = ws + 2 * (size_t)NTOT;
    float* part4   = ws + 3 * (size_t)NTOT;     // 4*262144
    float* ktvBuf  = part4 + 4 * 262144;        // 262144
    float* colpart = ktvBuf + 262144;           // 98304
    float* sc_qkv  = colpart + 98304;
    float* sh_qkv  = sc_qkv + 1536;
    float* sc_m    = sh_qkv + 1536;
    float* sh_m    = sc_m + 512;
    float* sc_p    = sh_m + 512;
    float* sh_p    = sc_p + 512;
    unsigned char* spk = (unsigned char*)(sh_p + 512);
    unsigned char* sq  = spk;
    unsigned char* sk  = spk + (size_t)NTOT;
    unsigned char* sv  = spk + 2 * (size_t)NTOT;
    unsigned char* sy0 = spk + 3 * (size_t)NTOT;
    unsigned char* sy1 = spk + 4 * (size_t)NTOT;

    // 1) QKV GEMM (fused column stats) -> pre S0,S1,S2
    gemm_f_k<<<dim3(32, 24), 256, 0, stream>>>(x, wq, wk, wv, S0, colpart, M);
    bnstats_final_k<<<6, 256, 0, stream>>>(colpart, 1536, 32, bn_g, bn_b, sc_qkv, sh_qkv);
    // 2) segmented BN+LIF -> q,k,v byte spikes
    lif_seg_k<<<dim3(48, 5), 256, 0, stream>>>(S0, sc_qkv, sh_qkv, nullptr, sq, 100, 64);
    // 3) global branch
    ktv_part_k<<<dim3(64, 4), 256, 0, stream>>>(sk, sv, part4);
    ktv_reduce_k<<<256, 256, 0, stream>>>(part4, ktvBuf);
    gapply_t_k<<<dim3(50, 8), 256, 0, stream>>>(sq, ktvBuf, S0, gscale);      // g_pre -> S0
    // 4) local branch -> l_pre S1
    local_k<<<dim3(16, 64), 256, 0, stream>>>(sq, sk, sv, S1, lscale);
    // 5) fused g/l/dw LIFs + mix + y0 LIF -> sy0 bytes
    branch_y0_k<<<dim3(16, 10), 256, 0, stream>>>(S0, S1, sv, w_dw, w_pw, sy0, 50, 64);
    // 6) mattn GEMM (byte A, fused stats) -> S2; BN; LIF -> sy1 bytes
    gemm_b_k<<<dim3(63, 8), 256, 0, stream>>>(sy0, w_mattn, S2, colpart, M);
    bnstats_final_k<<<2, 256, 0, stream>>>(colpart, 512, 63, bn_g + 1536, bn_b + 1536, sc_m, sh_m);
    lif_seg_k<<<dim3(16, 10), 256, 0, stream>>>(S2, sc_m, sh_m, nullptr, sy1, 50, 64);
    // 7) proj GEMM -> S0; BN; LIF -> out (fp32)
    gemm_b_k<<<dim3(63, 8), 256, 0, stream>>>(sy1, w_proj, S0, colpart, M);
    bnstats_final_k<<<2, 256, 0, stream>>>(colpart, 512, 63, bn_g + 2048, bn_b + 2048, sc_p, sh_p);
    lif_seg_k<<<dim3(16, 10), 256, 0, stream>>>(S0, sc_p, sh_p, out, nullptr, 50, 64);

    (void)in_sizes; (void)n_in; (void)out_size; (void)ws_size;
}

// Round 6
// 431.492 us; speedup vs baseline: 2.1500x; 1.0963x over previous
//
#include <hip/hip_runtime.h>
#include <cmath>

#define TT 500
#define NTOT 2048000       // T*B*C elements
#define WW 20

// ---------------------------------------------------------------------------
// QKV GEMM: A fp32 [M,512], 3 weights. BM=128,BN=128,BK=16, 8x8 microtile.
// Conflict-free staging (stride 132: 528B%128B-banks => 2-way = free).
// Fused column stats written into smem aliased over As/Bs after the k-loop.
// ---------------------------------------------------------------------------
__global__ __launch_bounds__(256) void gemm_f_k(
    const float* __restrict__ A,
    const float* __restrict__ W0, const float* __restrict__ W1, const float* __restrict__ W2,
    float* __restrict__ out, float* __restrict__ colpart, int M)
{
    __shared__ __align__(16) float smem[4224];   // As[16][132] | Bs[16][132]; red aliases
    float* As = smem;
    float* Bs = smem + 2112;
    int tid = threadIdx.x;
    int mBase = blockIdx.x * 128;
    int nBase = blockIdx.y * 128;
    int wsel = nBase >> 9;
    const float* Wp = (wsel == 0) ? W0 : ((wsel == 1) ? W1 : W2);
    int col0 = nBase & 511;
    int ty = tid >> 4, tx = tid & 15;
    int ldRow = tid >> 2;          // 0..63
    int ldK = (tid & 3) * 4;       // 0,4,8,12
    float acc[8][8] = {};
    float4 pa[2], pb[2];

    auto loadT = [&](int kt) {
#pragma unroll
        for (int l = 0; l < 2; ++l) {
            int m = mBase + ldRow + l * 64;
            pa[l] = make_float4(0.f, 0.f, 0.f, 0.f);
            if (m < M) pa[l] = *(const float4*)(A + (size_t)m * 512 + kt + ldK);
            pb[l] = *(const float4*)(Wp + (size_t)(col0 + ldRow + l * 64) * 512 + kt + ldK);
        }
    };
    loadT(0);
    for (int kt = 0; kt < 512; kt += 16) {
        __syncthreads();
#pragma unroll
        for (int l = 0; l < 2; ++l) {
            int row = ldRow + l * 64;
            As[(ldK + 0) * 132 + row] = pa[l].x; As[(ldK + 1) * 132 + row] = pa[l].y;
            As[(ldK + 2) * 132 + row] = pa[l].z; As[(ldK + 3) * 132 + row] = pa[l].w;
            Bs[(ldK + 0) * 132 + row] = pb[l].x; Bs[(ldK + 1) * 132 + row] = pb[l].y;
            Bs[(ldK + 2) * 132 + row] = pb[l].z; Bs[(ldK + 3) * 132 + row] = pb[l].w;
        }
        __syncthreads();
        if (kt + 16 < 512) loadT(kt + 16);
#pragma unroll
        for (int kk = 0; kk < 16; ++kk) {
            float4 a0 = *(const float4*)&As[kk * 132 + ty * 4];
            float4 a1 = *(const float4*)&As[kk * 132 + 64 + ty * 4];
            float4 b0 = *(const float4*)&Bs[kk * 132 + tx * 4];
            float4 b1 = *(const float4*)&Bs[kk * 132 + 64 + tx * 4];
            float av[8] = {a0.x, a0.y, a0.z, a0.w, a1.x, a1.y, a1.z, a1.w};
            float bv[8] = {b0.x, b0.y, b0.z, b0.w, b1.x, b1.y, b1.z, b1.w};
#pragma unroll
            for (int i = 0; i < 8; ++i)
#pragma unroll
                for (int j = 0; j < 8; ++j)
                    acc[i][j] = fmaf(av[i], bv[j], acc[i][j]);
        }
    }
    __syncthreads();   // done with As/Bs; reuse smem as red[16][128][2]
#pragma unroll
    for (int jj = 0; jj < 8; ++jj) {
        int colL = (jj < 4) ? (tx * 4 + jj) : (64 + tx * 4 + (jj - 4));
        float s = 0.f, q = 0.f;
#pragma unroll
        for (int i = 0; i < 8; ++i) { float v = acc[i][jj]; s += v; q = fmaf(v, v, q); }
        smem[(ty * 128 + colL) * 2 + 0] = s;
        smem[(ty * 128 + colL) * 2 + 1] = q;
    }
    __syncthreads();
    if (tid < 128) {
        float ss = 0.f, qq = 0.f;
#pragma unroll
        for (int r = 0; r < 16; ++r) {
            ss += smem[(r * 128 + tid) * 2 + 0];
            qq += smem[(r * 128 + tid) * 2 + 1];
        }
        colpart[((size_t)blockIdx.x * 1536 + nBase + tid) * 2 + 0] = ss;
        colpart[((size_t)blockIdx.x * 1536 + nBase + tid) * 2 + 1] = qq;
    }
    float* outp = out + (size_t)wsel * NTOT;
#pragma unroll
    for (int i = 0; i < 8; ++i) {
        int m = mBase + ((i < 4) ? (ty * 4 + i) : (64 + ty * 4 + (i - 4)));
        if (m < M) {
            *(float4*)(outp + (size_t)m * 512 + col0 + tx * 4) =
                make_float4(acc[i][0], acc[i][1], acc[i][2], acc[i][3]);
            *(float4*)(outp + (size_t)m * 512 + col0 + 64 + tx * 4) =
                make_float4(acc[i][4], acc[i][5], acc[i][6], acc[i][7]);
        }
    }
}

// ---------------------------------------------------------------------------
// Spike-input GEMM: A uchar [M,512]. BM=64,BN=128,BK=32, 4x8 microtile.
// k staged in two 16-groups so staging writes are 2-way (free). Fused stats.
// Grid (63, 4) = 252 blocks.
// ---------------------------------------------------------------------------
__global__ __launch_bounds__(256) void gemm_b_k(
    const unsigned char* __restrict__ A, const float* __restrict__ W,
    float* __restrict__ out, float* __restrict__ colpart, int M)
{
    __shared__ __align__(16) float smem[6400];   // As[32][68] | Bs[32][132]; red aliases
    float* As = smem;
    float* Bs = smem + 2176;
    int tid = threadIdx.x;
    int mBase = blockIdx.x * 64;
    int col0 = blockIdx.y * 128;
    int ty = tid >> 4, tx = tid & 15;
    int ldRow = tid >> 2;          // 0..63
    int ldK = (tid & 3) * 4;       // 0,4,8,12
    float acc[4][8] = {};
    uchar4 pa[2];
    float4 pb[2][2];

    auto loadT = [&](int kt) {
        int m = mBase + ldRow;
        if (m < M) {
            pa[0] = *(const uchar4*)(A + (size_t)m * 512 + kt + ldK);
            pa[1] = *(const uchar4*)(A + (size_t)m * 512 + kt + 16 + ldK);
        } else {
            pa[0] = make_uchar4(0, 0, 0, 0); pa[1] = make_uchar4(0, 0, 0, 0);
        }
#pragma unroll
        for (int l = 0; l < 2; ++l) {
            pb[l][0] = *(const float4*)(W + (size_t)(col0 + ldRow + l * 64) * 512 + kt + ldK);
            pb[l][1] = *(const float4*)(W + (size_t)(col0 + ldRow + l * 64) * 512 + kt + 16 + ldK);
        }
    };
    loadT(0);
    for (int kt = 0; kt < 512; kt += 32) {
        __syncthreads();
#pragma unroll
        for (int g = 0; g < 2; ++g) {
            As[(ldK + 16 * g + 0) * 68 + ldRow] = (float)pa[g].x;
            As[(ldK + 16 * g + 1) * 68 + ldRow] = (float)pa[g].y;
            As[(ldK + 16 * g + 2) * 68 + ldRow] = (float)pa[g].z;
            As[(ldK + 16 * g + 3) * 68 + ldRow] = (float)pa[g].w;
        }
#pragma unroll
        for (int l = 0; l < 2; ++l)
#pragma unroll
            for (int g = 0; g < 2; ++g) {
                int row = ldRow + l * 64;
                Bs[(ldK + 16 * g + 0) * 132 + row] = pb[l][g].x;
                Bs[(ldK + 16 * g + 1) * 132 + row] = pb[l][g].y;
                Bs[(ldK + 16 * g + 2) * 132 + row] = pb[l][g].z;
                Bs[(ldK + 16 * g + 3) * 132 + row] = pb[l][g].w;
            }
        __syncthreads();
        if (kt + 32 < 512) loadT(kt + 32);
#pragma unroll
        for (int kk = 0; kk < 32; ++kk) {
            float4 a0 = *(const float4*)&As[kk * 68 + ty * 4];
            float4 b0 = *(const float4*)&Bs[kk * 132 + tx * 4];
            float4 b1 = *(const float4*)&Bs[kk * 132 + 64 + tx * 4];
            float av[4] = {a0.x, a0.y, a0.z, a0.w};
            float bv[8] = {b0.x, b0.y, b0.z, b0.w, b1.x, b1.y, b1.z, b1.w};
#pragma unroll
            for (int i = 0; i < 4; ++i)
#pragma unroll
                for (int j = 0; j < 8; ++j)
                    acc[i][j] = fmaf(av[i], bv[j], acc[i][j]);
        }
    }
    __syncthreads();
#pragma unroll
    for (int jj = 0; jj < 8; ++jj) {
        int colL = (jj < 4) ? (tx * 4 + jj) : (64 + tx * 4 + (jj - 4));
        float s = 0.f, q = 0.f;
#pragma unroll
        for (int i = 0; i < 4; ++i) { float v = acc[i][jj]; s += v; q = fmaf(v, v, q); }
        smem[(ty * 128 + colL) * 2 + 0] = s;
        smem[(ty * 128 + colL) * 2 + 1] = q;
    }
    __syncthreads();
    if (tid < 128) {
        float ss = 0.f, qq = 0.f;
#pragma unroll
        for (int r = 0; r < 16; ++r) {
            ss += smem[(r * 128 + tid) * 2 + 0];
            qq += smem[(r * 128 + tid) * 2 + 1];
        }
        colpart[((size_t)blockIdx.x * 512 + col0 + tid) * 2 + 0] = ss;
        colpart[((size_t)blockIdx.x * 512 + col0 + tid) * 2 + 1] = qq;
    }
#pragma unroll
    for (int i = 0; i < 4; ++i) {
        int m = mBase + ty * 4 + i;
        if (m < M) {
            *(float4*)(out + (size_t)m * 512 + col0 + tx * 4) =
                make_float4(acc[i][0], acc[i][1], acc[i][2], acc[i][3]);
            *(float4*)(out + (size_t)m * 512 + col0 + 64 + tx * 4) =
                make_float4(acc[i][4], acc[i][5], acc[i][6], acc[i][7]);
        }
    }
}

// ---------------------------------------------------------------------------
// Time-segmented BN+LIF with INLINE stats finalize (f64, identical math).
// ---------------------------------------------------------------------------
__global__ __launch_bounds__(256) void lif_seg_k(
    const float* __restrict__ pre, const float* __restrict__ colpart, int CT, int chunks,
    const float* __restrict__ gamma, const float* __restrict__ beta,
    float* __restrict__ outF, unsigned char* __restrict__ outB, int segLen, int warm)
{
    int gid = blockIdx.x * 256 + threadIdx.x;
    int tensor = gid >> 12;
    int bc = gid & 4095;
    int ch = (tensor << 9) | (bc & 511);
    double s = 0.0, s2 = 0.0;
    for (int k = 0; k < chunks; ++k) {
        s  += (double)colpart[((size_t)k * CT + ch) * 2 + 0];
        s2 += (double)colpart[((size_t)k * CT + ch) * 2 + 1];
    }
    double mean = s / 4000.0;
    double var = s2 / 4000.0 - mean * mean;
    double scd = (double)gamma[ch] / sqrt(var + 1e-5);
    float sc = (float)scd;
    float sh = (float)((double)beta[ch] - mean * scd);
    const float* q0 = pre + (size_t)tensor * NTOT + bc;
    float* oF = outF ? outF + (size_t)tensor * NTOT + bc : nullptr;
    unsigned char* oB = outB ? outB + (size_t)tensor * NTOT + bc : nullptr;
    int t0 = blockIdx.y * segLen;
    int twarm = (t0 - warm > 0) ? (t0 - warm) : 0;
    int tend = (t0 + segLen < TT) ? (t0 + segLen) : TT;
    float v = 0.f;
    float b0[8];
#pragma unroll
    for (int j = 0; j < 8; ++j) {
        int tt = twarm + j;
        b0[j] = (tt < tend) ? q0[(size_t)tt * 4096] : 0.f;
    }
    for (int t = twarm; t < tend; t += 8) {
        float n0[8];
#pragma unroll
        for (int j = 0; j < 8; ++j) {
            int tt = t + 8 + j;
            n0[j] = (tt < tend) ? q0[(size_t)tt * 4096] : 0.f;
        }
#pragma unroll
        for (int j = 0; j < 8; ++j) {
            int tc = t + j;
            if (tc >= tend) break;
            float bnx = fmaf(b0[j], sc, sh);
            float h = fmaf(0.5f, v, bnx);
            float sp = (h >= 1.f) ? 1.f : 0.f;
            v = (h >= 1.f) ? 0.f : h;
            if (tc >= t0) {
                if (oB) oB[(size_t)tc * 4096] = (unsigned char)sp;
                else    oF[(size_t)tc * 4096] = sp;
            }
        }
#pragma unroll
        for (int j = 0; j < 8; ++j) b0[j] = n0[j];
    }
}

// ---------------------------------------------------------------------------
// KtV partials over t-quarters from byte spikes (exact integer sums).
// ---------------------------------------------------------------------------
__global__ __launch_bounds__(256) void ktv_part_k(
    const unsigned char* __restrict__ kspk, const unsigned char* __restrict__ vspk,
    float* __restrict__ part)
{
    __shared__ __align__(16) float kb[16][64], vb[16][64];
    int bh = blockIdx.x;
    int seg = blockIdx.y;
    int t0p = seg * 125, t1p = t0p + 125;
    int b = bh >> 3, h = bh & 7;
    int tid = threadIdx.x;
    int d1b = (tid >> 4) * 4, d2b = (tid & 15) * 4;
    size_t cb = (size_t)b * 512 + h * 64;
    int sRow = tid >> 4;
    int sD = (tid & 15) * 4;
    float acc[4][4] = {};
    uchar4 pk, pv;
    auto preload = [&](int tt) {
        int t = tt + sRow;
        if (t < t1p) {
            pk = *(const uchar4*)(kspk + (size_t)t * 4096 + cb + sD);
            pv = *(const uchar4*)(vspk + (size_t)t * 4096 + cb + sD);
        } else {
            pk = make_uchar4(0, 0, 0, 0); pv = make_uchar4(0, 0, 0, 0);
        }
    };
    preload(t0p);
    for (int tt = t0p; tt < t1p; tt += 16) {
        __syncthreads();
        kb[sRow][sD + 0] = (float)pk.x; kb[sRow][sD + 1] = (float)pk.y;
        kb[sRow][sD + 2] = (float)pk.z; kb[sRow][sD + 3] = (float)pk.w;
        vb[sRow][sD + 0] = (float)pv.x; vb[sRow][sD + 1] = (float)pv.y;
        vb[sRow][sD + 2] = (float)pv.z; vb[sRow][sD + 3] = (float)pv.w;
        __syncthreads();
        preload(tt + 16);
#pragma unroll
        for (int tl = 0; tl < 16; ++tl) {
            float4 k4 = *(const float4*)&kb[tl][d1b];
            float4 v4 = *(const float4*)&vb[tl][d2b];
            float ka[4] = {k4.x, k4.y, k4.z, k4.w};
            float va[4] = {v4.x, v4.y, v4.z, v4.w};
#pragma unroll
            for (int i = 0; i < 4; ++i)
#pragma unroll
                for (int j = 0; j < 4; ++j)
                    acc[i][j] = fmaf(ka[i], va[j], acc[i][j]);
        }
    }
    size_t ob = ((size_t)seg * 64 + bh) * 4096;
#pragma unroll
    for (int i = 0; i < 4; ++i)
        *(float4*)(part + ob + (size_t)(d1b + i) * 64 + d2b) =
            make_float4(acc[i][0], acc[i][1], acc[i][2], acc[i][3]);
}

__global__ __launch_bounds__(256) void ktv_reduce_k(
    const float* __restrict__ part, float* __restrict__ ktv)
{
    int i4 = (blockIdx.x * 256 + threadIdx.x) * 4;
    float4 a = *(const float4*)(part + i4);
    float4 b = *(const float4*)(part + 262144 + i4);
    float4 c = *(const float4*)(part + 2 * 262144 + i4);
    float4 d = *(const float4*)(part + 3 * 262144 + i4);
    *(float4*)(ktv + i4) = make_float4(((a.x + b.x) + c.x) + d.x,
                                       ((a.y + b.y) + c.y) + d.y,
                                       ((a.z + b.z) + c.z) + d.z,
                                       ((a.w + b.w) + c.w) + d.w);
}

// ---------------------------------------------------------------------------
// Global attention apply, t-tiled x10.
// ---------------------------------------------------------------------------
__global__ __launch_bounds__(256) void gapply_t_k(
    const unsigned char* __restrict__ sq, const float* __restrict__ ktv,
    float* __restrict__ gpre, float gscale)
{
    __shared__ float qs[10][512];
    int tid = threadIdx.x;
    int t0 = blockIdx.x * 10;
    int b = blockIdx.y;
    for (int i = tid; i < 1280; i += 256) {
        int t = i >> 7;
        int c4 = (i & 127) * 4;
        uchar4 u = *(const uchar4*)(sq + (size_t)(t0 + t) * 4096 + b * 512 + c4);
        qs[t][c4 + 0] = (float)u.x; qs[t][c4 + 1] = (float)u.y;
        qs[t][c4 + 2] = (float)u.z; qs[t][c4 + 3] = (float)u.w;
    }
    __syncthreads();
#pragma unroll
    for (int half = 0; half < 2; ++half) {
        int c = tid + half * 256;
        int h = c >> 6, dcol = c & 63;
        const float* kt = ktv + ((size_t)(b * 8 + h) * 64) * 64 + dcol;
        float acc[10] = {};
        for (int d1 = 0; d1 < 64; ++d1) {
            float kv = kt[(size_t)d1 * 64];
#pragma unroll
            for (int t = 0; t < 10; ++t)
                acc[t] = fmaf(qs[t][h * 64 + d1], kv, acc[t]);
        }
#pragma unroll
        for (int t = 0; t < 10; ++t)
            gpre[(size_t)(t0 + t) * 4096 + b * 512 + c] = acc[t] * gscale;
    }
}

// ---------------------------------------------------------------------------
// Local banded attention; LDS padded to 68 cols (kills 8-way read conflicts).
// ---------------------------------------------------------------------------
__global__ __launch_bounds__(256) void local_k(
    const unsigned char* __restrict__ qspk, const unsigned char* __restrict__ kspk,
    const unsigned char* __restrict__ vspk, float* __restrict__ lpre, float lscale)
{
    __shared__ __align__(16) float qs[32][68];
    __shared__ __align__(16) float ks[72][68];
    __shared__ __align__(16) float vs[72][68];
    __shared__ float sm[32][72];
    int t0 = blockIdx.x * 32;
    int bh = blockIdx.y;
    int b = bh >> 3, h = bh & 7;
    int tid = threadIdx.x;
    size_t cb = (size_t)b * 512 + h * 64;

    for (int i = tid; i < 512; i += 256) {
        int r = i >> 4, d4 = (i & 15) * 4;
        int t = t0 + r;
        if (t < TT) {
            uchar4 u = *(const uchar4*)(qspk + (size_t)t * 4096 + cb + d4);
            qs[r][d4 + 0] = (float)u.x; qs[r][d4 + 1] = (float)u.y;
            qs[r][d4 + 2] = (float)u.z; qs[r][d4 + 3] = (float)u.w;
        } else {
            qs[r][d4 + 0] = 0.f; qs[r][d4 + 1] = 0.f; qs[r][d4 + 2] = 0.f; qs[r][d4 + 3] = 0.f;
        }
    }
    for (int i = tid; i < 1152; i += 256) {
        int r = i >> 4, d4 = (i & 15) * 4;
        int u_ = t0 - WW + r;
        if (u_ >= 0 && u_ < TT) {
            uchar4 uk = *(const uchar4*)(kspk + (size_t)u_ * 4096 + cb + d4);
            uchar4 uv = *(const uchar4*)(vspk + (size_t)u_ * 4096 + cb + d4);
            ks[r][d4 + 0] = (float)uk.x; ks[r][d4 + 1] = (float)uk.y;
            ks[r][d4 + 2] = (float)uk.z; ks[r][d4 + 3] = (float)uk.w;
            vs[r][d4 + 0] = (float)uv.x; vs[r][d4 + 1] = (float)uv.y;
            vs[r][d4 + 2] = (float)uv.z; vs[r][d4 + 3] = (float)uv.w;
        } else {
            ks[r][d4 + 0] = 0.f; ks[r][d4 + 1] = 0.f; ks[r][d4 + 2] = 0.f; ks[r][d4 + 3] = 0.f;
            vs[r][d4 + 0] = 0.f; vs[r][d4 + 1] = 0.f; vs[r][d4 + 2] = 0.f; vs[r][d4 + 3] = 0.f;
        }
    }
    __syncthreads();

    int tA = tid >> 3;
    int ug = tid & 7;
    float4 qreg[16];
#pragma unroll
    for (int i = 0; i < 16; ++i) qreg[i] = *(const float4*)&qs[tA][i * 4];
#pragma unroll
    for (int ui = 0; ui < 9; ++ui) {
        int u = ug + ui * 8;
        float acc = 0.f;
#pragma unroll
        for (int i = 0; i < 16; ++i) {
            float4 k4 = *(const float4*)&ks[u][i * 4];
            acc = fmaf(qreg[i].x, k4.x, acc);
            acc = fmaf(qreg[i].y, k4.y, acc);
            acc = fmaf(qreg[i].z, k4.z, acc);
            acc = fmaf(qreg[i].w, k4.w, acc);
        }
        sm[tA][u] = acc;
    }
    __syncthreads();

#pragma unroll
    for (int oi = 0; oi < 2; ++oi) {
        int idx = tid + oi * 256;
        int t = idx >> 4;
        int dg = (idx & 15) * 4;
        float4 acc = make_float4(0.f, 0.f, 0.f, 0.f);
        for (int o = 0; o < 41; ++o) {
            int u = t + o;
            float s = sm[t][u];
            float4 v4 = *(const float4*)&vs[u][dg];
            acc.x = fmaf(s, v4.x, acc.x);
            acc.y = fmaf(s, v4.y, acc.y);
            acc.z = fmaf(s, v4.z, acc.z);
            acc.w = fmaf(s, v4.w, acc.w);
        }
        int tg = t0 + t;
        if (tg < TT) {
            acc.x *= lscale; acc.y *= lscale; acc.z *= lscale; acc.w *= lscale;
            *(float4*)(lpre + (size_t)tg * 4096 + cb + dg) = acc;
        }
    }
}

// ---------------------------------------------------------------------------
// Fused branch kernel: g-LIF + l-LIF + dwconv9-LIF + head-mix (wave shfl) +
// y0-LIF.  (unchanged from round 5)
// ---------------------------------------------------------------------------
__global__ __launch_bounds__(256) void branch_y0_k(
    const float* __restrict__ gpre, const float* __restrict__ lpre,
    const unsigned char* __restrict__ sv, const float* __restrict__ wdw,
    const float* __restrict__ wpw, unsigned char* __restrict__ sy0,
    int segLen, int warm)
{
    int tid = threadIdx.x;
    int wave = tid >> 6, lane = tid & 63;
    int gw = blockIdx.x * 4 + wave;    // 0..63
    int b = gw >> 3, dg = gw & 7;
    int h = lane >> 3, dl = lane & 7;
    int c = h * 64 + dg * 8 + dl;
    int base = b * 512 + c;
    float w9[9];
#pragma unroll
    for (int j = 0; j < 9; ++j) w9[j] = wdw[h * 9 + j];
    float w8[8];
#pragma unroll
    for (int j = 0; j < 8; ++j) w8[j] = wpw[h * 8 + j];
    int t0 = blockIdx.y * segLen;
    int twarm = (t0 - warm > 0) ? (t0 - warm) : 0;
    int tend = (t0 + segLen < TT) ? (t0 + segLen) : TT;
    float vg = 0.f, vl = 0.f, vd = 0.f, vy = 0.f;
    float win[12];
#pragma unroll
    for (int i = 0; i < 12; ++i) {
        int tt = twarm - 4 + i;
        win[i] = (tt >= 0 && tt < TT) ? (float)sv[(size_t)tt * 4096 + base] : 0.f;
    }
    float pg[4], pl[4], pv[4];
    auto pref = [&](int t) {
#pragma unroll
        for (int j = 0; j < 4; ++j) {
            int tt = t + j;
            bool in = tt < tend;
            pg[j] = in ? gpre[(size_t)tt * 4096 + base] : 0.f;
            pl[j] = in ? lpre[(size_t)tt * 4096 + base] : 0.f;
            int tv = t + 8 + j;
            pv[j] = (tv < TT) ? (float)sv[(size_t)tv * 4096 + base] : 0.f;
        }
    };
    pref(twarm);
    for (int t = twarm; t < tend; t += 4) {
        float cg[4], cl[4], cv[4];
#pragma unroll
        for (int j = 0; j < 4; ++j) { cg[j] = pg[j]; cl[j] = pl[j]; cv[j] = pv[j]; }
        pref(t + 4);
#pragma unroll
        for (int j = 0; j < 4; ++j) {
            int tc = t + j;
            if (tc >= tend) break;
            float x = 0.f;
#pragma unroll
            for (int q = 0; q < 9; ++q) x = fmaf(w9[q], win[j + q], x);
            float hd = fmaf(0.5f, vd, x);
            float sd = (hd >= 1.f) ? 1.f : 0.f;
            vd = (hd >= 1.f) ? 0.f : hd;
            float hg = fmaf(0.5f, vg, cg[j]);
            float sg = (hg >= 1.f) ? 1.f : 0.f;
            vg = (hg >= 1.f) ? 0.f : hg;
            float hl = fmaf(0.5f, vl, cl[j]);
            float sl = (hl >= 1.f) ? 1.f : 0.f;
            vl = (hl >= 1.f) ? 0.f : hl;
            float mix = 0.f;
#pragma unroll
            for (int h2 = 0; h2 < 8; ++h2)
                mix = fmaf(w8[h2], __shfl(sd, h2 * 8 + dl, 64), mix);
            float xy = (sg + sl) + mix;
            float hy = fmaf(0.5f, vy, xy);
            float sy = (hy >= 1.f) ? 1.f : 0.f;
            vy = (hy >= 1.f) ? 0.f : hy;
            if (tc >= t0) sy0[(size_t)tc * 4096 + base] = (unsigned char)sy;
        }
#pragma unroll
        for (int i = 0; i < 8; ++i) win[i] = win[i + 4];
#pragma unroll
        for (int i = 0; i < 4; ++i) win[8 + i] = cv[i];
    }
}

// ---------------------------------------------------------------------------
extern "C" void kernel_launch(void* const* d_in, const int* in_sizes, int n_in,
                              void* d_out, int out_size, void* d_ws, size_t ws_size,
                              hipStream_t stream)
{
    const float* x       = (const float*)d_in[0];
    const float* wq      = (const float*)d_in[1];
    const float* wk      = (const float*)d_in[2];
    const float* wv      = (const float*)d_in[3];
    const float* w_mattn = (const float*)d_in[4];
    const float* w_proj  = (const float*)d_in[5];
    const float* w_dw    = (const float*)d_in[6];
    const float* w_pw    = (const float*)d_in[7];
    const float* bn_g    = (const float*)d_in[8];
    const float* bn_b    = (const float*)d_in[9];
    float* out = (float*)d_out;
    float* ws = (float*)d_ws;

    float gs32 = (float)std::sqrt((double)(64 * 500));
    float gscale = (float)(1.0 / (double)gs32);
    float ls32 = (float)std::sqrt((double)(64 * 41));
    float lscale = (float)(1.0 / (double)ls32);
    const int M = TT * 8;   // 4000

    float* S0 = ws;
    float* S1 = ws + (size_t)NTOT;
    float* S2 = ws + 2 * (size_t)NTOT;
    float* part4   = ws + 3 * (size_t)NTOT;     // 4*262144
    float* ktvBuf  = part4 + 4 * 262144;        // 262144
    float* colpart = ktvBuf + 262144;           // 98304 (max: 32 chunks * 1536 * 2)
    unsigned char* spk = (unsigned char*)(colpart + 98304);
    unsigned char* sq  = spk;
    unsigned char* sk  = spk + (size_t)NTOT;
    unsigned char* sv  = spk + 2 * (size_t)NTOT;
    unsigned char* sy0 = spk + 3 * (size_t)NTOT;
    unsigned char* sy1 = spk + 4 * (size_t)NTOT;

    // 1) QKV GEMM (fused column stats) -> pre S0,S1,S2; stats in colpart[32][1536]
    gemm_f_k<<<dim3(32, 12), 256, 0, stream>>>(x, wq, wk, wv, S0, colpart, M);
    // 2) segmented BN+LIF (inline stats finalize) -> q,k,v byte spikes
    lif_seg_k<<<dim3(48, 5), 256, 0, stream>>>(S0, colpart, 1536, 32, bn_g, bn_b,
                                               nullptr, sq, 100, 64);
    // 3) global branch
    ktv_part_k<<<dim3(64, 4), 256, 0, stream>>>(sk, sv, part4);
    ktv_reduce_k<<<256, 256, 0, stream>>>(part4, ktvBuf);
    gapply_t_k<<<dim3(50, 8), 256, 0, stream>>>(sq, ktvBuf, S0, gscale);      // g_pre -> S0
    // 4) local branch -> l_pre S1
    local_k<<<dim3(16, 64), 256, 0, stream>>>(sq, sk, sv, S1, lscale);
    // 5) fused g/l/dw LIFs + mix + y0 LIF -> sy0 bytes
    branch_y0_k<<<dim3(16, 10), 256, 0, stream>>>(S0, S1, sv, w_dw, w_pw, sy0, 50, 64);
    // 6) mattn GEMM (byte A, fused stats, 63x4) -> S2; LIF -> sy1 bytes
    gemm_b_k<<<dim3(63, 4), 256, 0, stream>>>(sy0, w_mattn, S2, colpart, M);
    lif_seg_k<<<dim3(16, 10), 256, 0, stream>>>(S2, colpart, 512, 63, bn_g + 1536,
                                                bn_b + 1536, nullptr, sy1, 50, 64);
    // 7) proj GEMM -> S0; LIF -> out (fp32)
    gemm_b_k<<<dim3(63, 4), 256, 0, stream>>>(sy1, w_proj, S0, colpart, M);
    lif_seg_k<<<dim3(16, 10), 256, 0, stream>>>(S0, colpart, 512, 63, bn_g + 2048,
                                                bn_b + 2048, out, nullptr, 50, 64);

    (void)in_sizes; (void)n_in; (void)out_size; (void)ws_size;
}